// Round 1
// baseline (508.207 us; speedup 1.0000x reference)
//
#include <hip/hip_runtime.h>

typedef unsigned short u16;
typedef unsigned int u32;
typedef float f32x4 __attribute__((ext_vector_type(4)));
typedef short s16x8 __attribute__((ext_vector_type(8)));

#define T_ 4
#define B_ 16
#define C_ 512
#define N_ 1024
#define YSZ 33554432  // 64*512*1024 (y output elements); attn follows in d_out

// ---- bf16 helpers (manual RNE) ----
__device__ __forceinline__ u16 f2bf(float f) {
  u32 u = __float_as_uint(f);
  u32 r = u + 0x7FFFu + ((u >> 16) & 1u);
  return (u16)(r >> 16);
}
__device__ __forceinline__ float bf2f(u16 h) { return __uint_as_float(((u32)h) << 16); }

// ---- async global->LDS, 16B per lane, wave-uniform LDS base ----
__device__ __forceinline__ void async16(const void* g, void* l) {
  __builtin_amdgcn_global_load_lds((const __attribute__((address_space(1))) void*)g,
                                   (__attribute__((address_space(3))) void*)l, 16, 0, 0);
}

#define LDV(p) (*(const s16x8*)(p))
#define MFMA_(a, b, c) __builtin_amdgcn_mfma_f32_16x16x32_bf16(a, b, c, 0, 0, 0)

// 16 MFMAs: ti = P, P+1 over tj 0..3, hi then lo into same acc (order preserved
// per-accumulator vs the previous kernel: kk0-hi, kk0-lo, kk1-hi, kk1-lo).
#define MFMA16(P)                                                                      \
  do {                                                                                 \
    acc[P][0] = MFMA_(ahA, bf0, acc[P][0]); acc[P][0] = MFMA_(alA, bf0, acc[P][0]);    \
    acc[P][1] = MFMA_(ahA, bf1, acc[P][1]); acc[P][1] = MFMA_(alA, bf1, acc[P][1]);    \
    acc[P][2] = MFMA_(ahA, bf2, acc[P][2]); acc[P][2] = MFMA_(alA, bf2, acc[P][2]);    \
    acc[P][3] = MFMA_(ahA, bf3, acc[P][3]); acc[P][3] = MFMA_(alA, bf3, acc[P][3]);    \
    acc[(P)+1][0] = MFMA_(ahB, bf0, acc[(P)+1][0]);                                    \
    acc[(P)+1][0] = MFMA_(alB, bf0, acc[(P)+1][0]);                                    \
    acc[(P)+1][1] = MFMA_(ahB, bf1, acc[(P)+1][1]);                                    \
    acc[(P)+1][1] = MFMA_(alB, bf1, acc[(P)+1][1]);                                    \
    acc[(P)+1][2] = MFMA_(ahB, bf2, acc[(P)+1][2]);                                    \
    acc[(P)+1][2] = MFMA_(alB, bf2, acc[(P)+1][2]);                                    \
    acc[(P)+1][3] = MFMA_(ahB, bf3, acc[(P)+1][3]);                                    \
    acc[(P)+1][3] = MFMA_(alB, bf3, acc[(P)+1][3]);                                    \
  } while (0)

// =====================================================================
// prep: split q_w/k_w into bf16 hi|lo concat [512][1024]; proj_w -> bf16;
//       BN constants (inv, bias) for q/k/p into consts[].
// =====================================================================
__global__ void prep_kernel(const float* __restrict__ qw, const float* __restrict__ kw,
                            const float* __restrict__ pw,
                            const float* __restrict__ qg, const float* __restrict__ qb,
                            const float* __restrict__ qm, const float* __restrict__ qv,
                            const float* __restrict__ kg, const float* __restrict__ kb,
                            const float* __restrict__ km, const float* __restrict__ kv,
                            const float* __restrict__ pg, const float* __restrict__ pbt,
                            const float* __restrict__ pm, const float* __restrict__ pv,
                            u16* __restrict__ whlq, u16* __restrict__ whlk,
                            u16* __restrict__ pwb, float* __restrict__ consts) {
  int blk = blockIdx.x, tid = threadIdx.x;
  if (blk < 512) {
    int d = blk;
    for (int c = tid; c < 512; c += 256) {
      float w = qw[d * 512 + c];
      u16 hi = f2bf(w);
      whlq[d * 1024 + c] = hi;
      whlq[d * 1024 + 512 + c] = f2bf(w - bf2f(hi));
      w = kw[d * 512 + c];
      hi = f2bf(w);
      whlk[d * 1024 + c] = hi;
      whlk[d * 1024 + 512 + c] = f2bf(w - bf2f(hi));
      pwb[d * 512 + c] = f2bf(pw[d * 512 + c]);
    }
  } else {
    for (int c = tid; c < 512; c += 256) {
      float inv = qg[c] / sqrtf(qv[c] + 1e-5f);
      consts[c] = inv; consts[512 + c] = qb[c] - qm[c] * inv;
      inv = kg[c] / sqrtf(kv[c] + 1e-5f);
      consts[1024 + c] = inv; consts[1536 + c] = kb[c] - km[c] * inv;
      inv = pg[c] / sqrtf(pv[c] + 1e-5f);
      consts[2048 + c] = inv; consts[2560 + c] = pbt[c] - pm[c] * inv;
    }
  }
}

// =====================================================================
// lif_x: x[t,b,c,n] f32 -> spikes xs[t,b,n,c] bf16 (LDS transpose).
// =====================================================================
__global__ __launch_bounds__(256) void lifx_kernel(const float* __restrict__ x,
                                                   u16* __restrict__ xs) {
  int b = blockIdx.z;
  int cbase = blockIdx.y * 64, nbase = blockIdx.x * 64;
  int tid = threadIdx.x;
  int c_l = tid >> 6, n_l = tid & 63;
  __shared__ __align__(16) u16 tile[64 * 72];
  float v[16];
#pragma unroll
  for (int i = 0; i < 16; ++i) v[i] = 0.f;
  for (int t = 0; t < 4; ++t) {
    const float* xp = x + ((size_t)(t * 16 + b) * 512 + cbase + c_l * 16) * 1024 + nbase + n_l;
#pragma unroll
    for (int i = 0; i < 16; ++i) {
      float xv = xp[(size_t)i * 1024];
      float vn = v[i] + 0.5f * (xv - v[i]);   // v + (x-v)/TAU, TAU=2 (bit-exact vs np)
      bool s = vn >= 1.0f;
      tile[n_l * 72 + c_l * 16 + i] = s ? 0x3F80 : 0;
      v[i] = s ? 0.f : vn;
    }
    __syncthreads();
    u16* yb = xs + ((size_t)(t * 16 + b) * 1024 + nbase) * 512 + cbase;
#pragma unroll
    for (int e = 0; e < 2; ++e) {
      int chunk = tid * 2 + e;
      int n = chunk >> 3, c0 = (chunk & 7) * 8;
      *(uint4*)&yb[(size_t)n * 512 + c0] = *(const uint4*)&tile[n * 72 + c0];
    }
    __syncthreads();
  }
}

// =====================================================================
// Shared phase-pipelined K-loop for gemm_q / gemm_k.
// Tile BM=128 x BN=256, 8 waves (2m x 4n), per-wave 64x64 output.
// LDS: 2 x 64 KB buffers: [Ah 128x64 | Al 128x64 | B 256x64] (u16).
// Per K-step (BK=64): 4 phases of 16 MFMAs each; all 8 next-step
// global_load_lds issues front-loaded into phases 0-1 (issue early,
// drain late at the step-boundary __syncthreads).
// =====================================================================
__device__ __forceinline__ void qk_mainloop(
    const u16* __restrict__ A, const u16* __restrict__ Bt, u16* sm,
    int m_blk, int n_blk, int wid, int wm, int wn, int quad, int l16,
    int srow, int scol, int rxor, f32x4 (&acc)[4][4]) {
  const int aoff = (wm * 64 + l16) * 64;
  const int boff = 16384 + (wn * 64 + l16) * 64;
  const int slot0 = (quad ^ rxor) * 8;
  const int slot1 = ((4 + quad) ^ rxor) * 8;
  const int arow = wid * 8 + srow;

  // prologue: stage k0=0 into buf0
#pragma unroll
  for (int j = 0; j < 2; ++j) {
    const u16* src = A + (size_t)(m_blk + j * 64 + arow) * 1024 + scol;
    async16(src,       sm + (j * 8 + wid) * 512);
    async16(src + 512, sm + 8192 + (j * 8 + wid) * 512);
  }
#pragma unroll
  for (int j = 0; j < 4; ++j)
    async16(Bt + (size_t)(n_blk + j * 64 + arow) * 512 + scol,
            sm + 16384 + (j * 8 + wid) * 512);
  __syncthreads();

  int cur = 0;
  for (int s = 0; s < 8; ++s) {
    u16* S = sm + cur * 32768;
    u16* Sn = sm + (cur ^ 1) * 32768;
    const int k0n = (s + 1) * 64;
    const bool pf = (s < 7);
    s16x8 ahA, ahB, alA, alB, bf0, bf1, bf2, bf3;

    // ---- phase 0: kk0, ti{0,1} + B(kk0); prefetch next A hi/lo ----
    ahA = LDV(S + aoff + slot0);
    ahB = LDV(S + aoff + 1024 + slot0);
    alA = LDV(S + 8192 + aoff + slot0);
    alB = LDV(S + 8192 + aoff + 1024 + slot0);
    bf0 = LDV(S + boff + slot0);
    bf1 = LDV(S + boff + 1024 + slot0);
    bf2 = LDV(S + boff + 2048 + slot0);
    bf3 = LDV(S + boff + 3072 + slot0);
    if (pf) {
#pragma unroll
      for (int j = 0; j < 2; ++j) {
        const u16* src = A + (size_t)(m_blk + j * 64 + arow) * 1024 + k0n + scol;
        async16(src,       Sn + (j * 8 + wid) * 512);
        async16(src + 512, Sn + 8192 + (j * 8 + wid) * 512);
      }
    }
    __builtin_amdgcn_s_barrier();
    __builtin_amdgcn_s_setprio(1);
    MFMA16(0);
    __builtin_amdgcn_s_setprio(0);
    __builtin_amdgcn_s_barrier();

    // ---- phase 1: kk0, ti{2,3} (B frags held); prefetch next B ----
    ahA = LDV(S + aoff + 2048 + slot0);
    ahB = LDV(S + aoff + 3072 + slot0);
    alA = LDV(S + 8192 + aoff + 2048 + slot0);
    alB = LDV(S + 8192 + aoff + 3072 + slot0);
    if (pf) {
#pragma unroll
      for (int j = 0; j < 4; ++j)
        async16(Bt + (size_t)(n_blk + j * 64 + arow) * 512 + k0n + scol,
                Sn + 16384 + (j * 8 + wid) * 512);
    }
    __builtin_amdgcn_s_barrier();
    __builtin_amdgcn_s_setprio(1);
    MFMA16(2);
    __builtin_amdgcn_s_setprio(0);
    __builtin_amdgcn_s_barrier();

    // ---- phase 2: kk1, ti{0,1} + B(kk1) ----
    ahA = LDV(S + aoff + slot1);
    ahB = LDV(S + aoff + 1024 + slot1);
    alA = LDV(S + 8192 + aoff + slot1);
    alB = LDV(S + 8192 + aoff + 1024 + slot1);
    bf0 = LDV(S + boff + slot1);
    bf1 = LDV(S + boff + 1024 + slot1);
    bf2 = LDV(S + boff + 2048 + slot1);
    bf3 = LDV(S + boff + 3072 + slot1);
    __builtin_amdgcn_s_barrier();
    __builtin_amdgcn_s_setprio(1);
    MFMA16(0);
    __builtin_amdgcn_s_setprio(0);
    __builtin_amdgcn_s_barrier();

    // ---- phase 3: kk1, ti{2,3}; step boundary drains vmcnt ----
    ahA = LDV(S + aoff + 2048 + slot1);
    ahB = LDV(S + aoff + 3072 + slot1);
    alA = LDV(S + 8192 + aoff + 2048 + slot1);
    alB = LDV(S + 8192 + aoff + 3072 + slot1);
    __builtin_amdgcn_s_barrier();
    __builtin_amdgcn_s_setprio(1);
    MFMA16(2);
    __builtin_amdgcn_s_setprio(0);
    __syncthreads();  // full drain: next-step buffer ready, reads of cur done
    cur ^= 1;
  }
}

// =====================================================================
// gemm_q: fused conv_q + BN + LIF + head-sum + attn-LIF.
// =====================================================================
__global__ __launch_bounds__(512, 2) void gemm_q_kernel(
    const u16* __restrict__ A, const u16* __restrict__ Bbase,
    const float* __restrict__ consts, float* __restrict__ dout) {
  extern __shared__ u16 sm[];
  const int tid = threadIdx.x;
  const int lane = tid & 63, wid = tid >> 6;
  const int wm = wid >> 2, wn = wid & 3;
  const int quad = lane >> 4, l16 = lane & 15;
  const int b = blockIdx.z;
  const int m_blk = blockIdx.y * 128, n_blk = blockIdx.x * 256;
  const int srow = lane >> 3;
  const int scol = (((lane & 7) ^ srow) & 7) * 8;
  const int rxor = l16 & 7;
  float v[64];  // LIF state, [ti*4+tj]*4+r
#pragma unroll
  for (int i = 0; i < 64; ++i) v[i] = 0.f;
  float va[4] = {0.f, 0.f, 0.f, 0.f};  // attn LIF state per tj

  for (int t = 0; t < 4; ++t) {
    f32x4 acc[4][4];
    const f32x4 zero = {0.f, 0.f, 0.f, 0.f};
#pragma unroll
    for (int i = 0; i < 4; ++i)
#pragma unroll
      for (int j = 0; j < 4; ++j) acc[i][j] = zero;
    const u16* Bt = Bbase + (size_t)(t * 16 + b) * (N_ * C_);

    qk_mainloop(A, Bt, sm, m_blk, n_blk, wid, wm, wn, quad, l16, srow, scol, rxor, acc);

    // epilogue: BN + LIF + head partial sums
    float qp[4] = {0.f, 0.f, 0.f, 0.f};
#pragma unroll
    for (int ti = 0; ti < 4; ++ti) {
#pragma unroll
      for (int r = 0; r < 4; ++r) {
        int row = m_blk + wm * 64 + ti * 16 + quad * 4 + r;
        float iv = consts[row], ib = consts[512 + row];
#pragma unroll
        for (int tj = 0; tj < 4; ++tj) {
          float bnv = acc[ti][tj][r] * iv + ib;
          float vv = v[(ti * 4 + tj) * 4 + r];
          float vn = vv + 0.5f * (bnv - vv);
          bool s = vn >= 1.0f;
          v[(ti * 4 + tj) * 4 + r] = s ? 0.f : vn;
          qp[tj] += s ? 1.f : 0.f;
        }
      }
    }
    int h = (m_blk >> 6) + wm;
#pragma unroll
    for (int tj = 0; tj < 4; ++tj) {
      float q = qp[tj];
      q += __shfl_xor(q, 16, 64);
      q += __shfl_xor(q, 32, 64);  // sum over quad -> full 64-channel head sum
      float vn = va[tj] + 0.5f * (q - va[tj]);  // exact dyadic
      bool s = vn >= 0.5f;
      va[tj] = s ? 0.f : vn;
      if (quad == 0) {
        int col = n_blk + wn * 64 + tj * 16 + l16;
        dout[(size_t)YSZ + ((size_t)(t * 16 + b) * 8 + h) * 1024 + col] = s ? 1.f : 0.f;
      }
    }
  }
}

// =====================================================================
// gemm_k: fused conv_k + BN + LIF + (spike * attn) -> y[t,b,n,c] bf16.
// Transpose via LDS tile aliased onto buf0 (dead after K-loop), stride 132.
// =====================================================================
__global__ __launch_bounds__(512, 2) void gemm_k_kernel(
    const u16* __restrict__ A, const u16* __restrict__ Bbase,
    const float* __restrict__ consts, const float* __restrict__ dout,
    u16* __restrict__ y) {
  extern __shared__ u16 sm[];
  const int tid = threadIdx.x;
  const int lane = tid & 63, wid = tid >> 6;
  const int wm = wid >> 2, wn = wid & 3;
  const int quad = lane >> 4, l16 = lane & 15;
  const int b = blockIdx.z;
  const int m_blk = blockIdx.y * 128, n_blk = blockIdx.x * 256;
  const int srow = lane >> 3;
  const int scol = (((lane & 7) ^ srow) & 7) * 8;
  const int rxor = l16 & 7;
  float v[64];
#pragma unroll
  for (int i = 0; i < 64; ++i) v[i] = 0.f;

  for (int t = 0; t < 4; ++t) {
    f32x4 acc[4][4];
    const f32x4 zero = {0.f, 0.f, 0.f, 0.f};
#pragma unroll
    for (int i = 0; i < 4; ++i)
#pragma unroll
      for (int j = 0; j < 4; ++j) acc[i][j] = zero;
    const u16* Bt = Bbase + (size_t)(t * 16 + b) * (N_ * C_);

    qk_mainloop(A, Bt, sm, m_blk, n_blk, wid, wm, wn, quad, l16, srow, scol, rxor, acc);

    // attn for this block's head/cols (written by gemm_q)
    int h = (m_blk >> 6) + wm;
    float at[4];
#pragma unroll
    for (int tj = 0; tj < 4; ++tj) {
      int col = n_blk + wn * 64 + tj * 16 + l16;
      at[tj] = dout[(size_t)YSZ + ((size_t)(t * 16 + b) * 8 + h) * 1024 + col];
    }

    // epilogue: BN + LIF + mask, pack 4 consecutive c into LDS transpose tile
    u16* Ys = sm;  // 256 x 132 u16, aliases buf0 (dead after K-loop)
#pragma unroll
    for (int ti = 0; ti < 4; ++ti) {
      u16 pk[4][4];
#pragma unroll
      for (int r = 0; r < 4; ++r) {
        int row = m_blk + wm * 64 + ti * 16 + quad * 4 + r;
        float iv = consts[1024 + row], ib = consts[1536 + row];
#pragma unroll
        for (int tj = 0; tj < 4; ++tj) {
          float bnv = acc[ti][tj][r] * iv + ib;
          float vv = v[(ti * 4 + tj) * 4 + r];
          float vn = vv + 0.5f * (bnv - vv);
          bool s = vn >= 1.0f;
          v[(ti * 4 + tj) * 4 + r] = s ? 0.f : vn;
          pk[tj][r] = (s && at[tj] != 0.f) ? 0x3F80 : 0;
        }
      }
#pragma unroll
      for (int tj = 0; tj < 4; ++tj) {
        int n_loc = wn * 64 + tj * 16 + l16;
        int c_loc = wm * 64 + ti * 16 + quad * 4;
        u32 lo2 = (u32)pk[tj][0] | ((u32)pk[tj][1] << 16);
        u32 hi2 = (u32)pk[tj][2] | ((u32)pk[tj][3] << 16);
        uint2 pv2; pv2.x = lo2; pv2.y = hi2;
        *(uint2*)&Ys[n_loc * 132 + c_loc] = pv2;
      }
    }
    __syncthreads();
    // coop store: 256 rows(n) x 128 u16(c) coalesced
    u16* yb = y + ((size_t)(t * 16 + b) * 1024 + n_blk) * 512 + m_blk;
#pragma unroll
    for (int p = 0; p < 8; ++p) {
      int idx = p * 512 + tid;
      int rown = idx >> 4, ch = (idx & 15) * 8;
      *(uint4*)&yb[(size_t)rown * 512 + ch] = *(const uint4*)&Ys[rown * 132 + ch];
    }
    __syncthreads();  // Ys dead before next t's staging overwrites sm
  }
}

// =====================================================================
// gemm_proj: out[d,n] = (sum_k pw[d,k]*y[n,k] + proj_b)*p_inv + p_bias.
// =====================================================================
__global__ __launch_bounds__(256, 3) void gemm_proj_kernel(
    const u16* __restrict__ A, const u16* __restrict__ Bbase,
    float* __restrict__ outP, const float* __restrict__ projb,
    const float* __restrict__ consts) {
  const int tid = threadIdx.x;
  const int lane = tid & 63, w = tid >> 6;
  const int wm = w >> 1, wn = w & 1;
  const int quad = lane >> 4, l16 = lane & 15;
  const int tb = blockIdx.z;
  const int m_blk = blockIdx.y * 128, n_blk = blockIdx.x * 128;
  const int srow = lane >> 3;
  const int scol = (((lane & 7) ^ srow) & 7) * 8;
  __shared__ __align__(16) u16 As[128 * 64];
  __shared__ __align__(16) u16 Bs[128 * 64];
  f32x4 acc[4][4];
  const f32x4 zero = {0.f, 0.f, 0.f, 0.f};
#pragma unroll
  for (int i = 0; i < 4; ++i)
#pragma unroll
    for (int j = 0; j < 4; ++j) acc[i][j] = zero;
  const u16* Bt = Bbase + (size_t)tb * (N_ * C_);
  const int rxor = l16 & 7;

  for (int k0 = 0; k0 < 512; k0 += 64) {
#pragma unroll
    for (int i = 0; i < 4; ++i) {
      int r = i * 32 + w * 8 + srow;
      async16(A + (size_t)(m_blk + r) * 512 + k0 + scol, &As[(i * 32 + w * 8) * 64]);
      async16(Bt + (size_t)(n_blk + r) * 512 + k0 + scol, &Bs[(i * 32 + w * 8) * 64]);
    }
    __syncthreads();
#pragma unroll
    for (int kk = 0; kk < 2; ++kk) {
      s16x8 af[4], bf[4];
      const int slot = ((kk * 4 + quad) ^ rxor) * 8;
#pragma unroll
      for (int ti = 0; ti < 4; ++ti)
        af[ti] = *(const s16x8*)&As[(wm * 64 + ti * 16 + l16) * 64 + slot];
#pragma unroll
      for (int tj = 0; tj < 4; ++tj)
        bf[tj] = *(const s16x8*)&Bs[(wn * 64 + tj * 16 + l16) * 64 + slot];
#pragma unroll
      for (int ti = 0; ti < 4; ++ti)
#pragma unroll
        for (int tj = 0; tj < 4; ++tj)
          acc[ti][tj] = __builtin_amdgcn_mfma_f32_16x16x32_bf16(af[ti], bf[tj], acc[ti][tj], 0, 0, 0);
    }
    __syncthreads();
  }

  const float* pinv = consts + 2048;
  const float* pb2 = consts + 2560;
  float* o = outP + (size_t)tb * (C_ * N_);
#pragma unroll
  for (int ti = 0; ti < 4; ++ti) {
    int row0 = m_blk + wm * 64 + ti * 16 + quad * 4;
#pragma unroll
    for (int r = 0; r < 4; ++r) {
      int row = row0 + r;
      float bi = projb[row], piv = pinv[row], pbi = pb2[row];
#pragma unroll
      for (int tj = 0; tj < 4; ++tj) {
        int col = n_blk + wn * 64 + tj * 16 + l16;
        o[(size_t)row * N_ + col] = (acc[ti][tj][r] + bi) * piv + pbi;
      }
    }
  }
}

// =====================================================================
extern "C" void kernel_launch(void* const* d_in, const int* in_sizes, int n_in,
                              void* d_out, int out_size, void* d_ws, size_t ws_size,
                              hipStream_t stream) {
  const float* x   = (const float*)d_in[0];
  const float* qw  = (const float*)d_in[1];
  const float* qg  = (const float*)d_in[2];
  const float* qb  = (const float*)d_in[3];
  const float* qm  = (const float*)d_in[4];
  const float* qv  = (const float*)d_in[5];
  const float* kw  = (const float*)d_in[6];
  const float* kg  = (const float*)d_in[7];
  const float* kb  = (const float*)d_in[8];
  const float* km  = (const float*)d_in[9];
  const float* kv  = (const float*)d_in[10];
  const float* pw  = (const float*)d_in[11];
  const float* pb  = (const float*)d_in[12];
  const float* pg  = (const float*)d_in[13];
  const float* pbt = (const float*)d_in[14];
  const float* pm  = (const float*)d_in[15];
  const float* pv  = (const float*)d_in[16];
  float* out = (float*)d_out;
  char* ws = (char*)d_ws;

  u16* xs       = (u16*)ws;                    // 64 MB spikes [t,b,n,c]
  u16* y2       = (u16*)(ws + 67108864);       // 64 MB y [t,b,n,c]
  u16* whlq     = (u16*)(ws + 201326592);
  u16* whlk     = (u16*)(ws + 202375168);
  u16* pwb      = (u16*)(ws + 203423744);
  float* consts = (float*)(ws + 203948032);

  static int attr_done = 0;
  if (!attr_done) {
    hipFuncSetAttribute((const void*)gemm_q_kernel,
                        hipFuncAttributeMaxDynamicSharedMemorySize, 131072);
    hipFuncSetAttribute((const void*)gemm_k_kernel,
                        hipFuncAttributeMaxDynamicSharedMemorySize, 131072);
    attr_done = 1;
  }

  prep_kernel<<<513, 256, 0, stream>>>(qw, kw, pw, qg, qb, qm, qv, kg, kb, km, kv,
                                       pg, pbt, pm, pv, whlq, whlk, pwb, consts);
  lifx_kernel<<<dim3(16, 8, 16), 256, 0, stream>>>(x, xs);
  gemm_q_kernel<<<dim3(4, 4, 16), 512, 131072, stream>>>(whlq, xs, consts, out);
  gemm_k_kernel<<<dim3(4, 4, 16), 512, 131072, stream>>>(whlk, xs, consts, out, y2);
  gemm_proj_kernel<<<dim3(8, 4, 64), 256, 0, stream>>>(pwb, y2, out, pb, consts);
}

// Round 2
// 475.228 us; speedup vs baseline: 1.0694x; 1.0694x over previous
//
#include <hip/hip_runtime.h>

typedef unsigned short u16;
typedef unsigned int u32;
typedef float f32x4 __attribute__((ext_vector_type(4)));
typedef short s16x8 __attribute__((ext_vector_type(8)));

#define T_ 4
#define B_ 16
#define C_ 512
#define N_ 1024
#define YSZ 33554432  // 64*512*1024 (y output elements); attn follows in d_out

// ---- bf16 helpers (manual RNE) ----
__device__ __forceinline__ u16 f2bf(float f) {
  u32 u = __float_as_uint(f);
  u32 r = u + 0x7FFFu + ((u >> 16) & 1u);
  return (u16)(r >> 16);
}
__device__ __forceinline__ float bf2f(u16 h) { return __uint_as_float(((u32)h) << 16); }

// ---- async global->LDS, 16B per lane, wave-uniform LDS base ----
__device__ __forceinline__ void async16(const void* g, void* l) {
  __builtin_amdgcn_global_load_lds((const __attribute__((address_space(1))) void*)g,
                                   (__attribute__((address_space(3))) void*)l, 16, 0, 0);
}

// =====================================================================
// prep: split q_w/k_w into bf16 hi|lo concat [512][1024]; proj_w -> bf16;
//       BN constants (inv, bias) for q/k/p into consts[].
// =====================================================================
__global__ void prep_kernel(const float* __restrict__ qw, const float* __restrict__ kw,
                            const float* __restrict__ pw,
                            const float* __restrict__ qg, const float* __restrict__ qb,
                            const float* __restrict__ qm, const float* __restrict__ qv,
                            const float* __restrict__ kg, const float* __restrict__ kb,
                            const float* __restrict__ km, const float* __restrict__ kv,
                            const float* __restrict__ pg, const float* __restrict__ pbt,
                            const float* __restrict__ pm, const float* __restrict__ pv,
                            u16* __restrict__ whlq, u16* __restrict__ whlk,
                            u16* __restrict__ pwb, float* __restrict__ consts) {
  int blk = blockIdx.x, tid = threadIdx.x;
  if (blk < 512) {
    int d = blk;
    for (int c = tid; c < 512; c += 256) {
      float w = qw[d * 512 + c];
      u16 hi = f2bf(w);
      whlq[d * 1024 + c] = hi;
      whlq[d * 1024 + 512 + c] = f2bf(w - bf2f(hi));
      w = kw[d * 512 + c];
      hi = f2bf(w);
      whlk[d * 1024 + c] = hi;
      whlk[d * 1024 + 512 + c] = f2bf(w - bf2f(hi));
      pwb[d * 512 + c] = f2bf(pw[d * 512 + c]);
    }
  } else {
    for (int c = tid; c < 512; c += 256) {
      float inv = qg[c] / sqrtf(qv[c] + 1e-5f);
      consts[c] = inv; consts[512 + c] = qb[c] - qm[c] * inv;
      inv = kg[c] / sqrtf(kv[c] + 1e-5f);
      consts[1024 + c] = inv; consts[1536 + c] = kb[c] - km[c] * inv;
      inv = pg[c] / sqrtf(pv[c] + 1e-5f);
      consts[2048 + c] = inv; consts[2560 + c] = pbt[c] - pm[c] * inv;
    }
  }
}

// =====================================================================
// lif_x: x[t,b,c,n] f32 -> spikes xs[t,b,n,c] bf16 (LDS transpose).
// =====================================================================
__global__ __launch_bounds__(256) void lifx_kernel(const float* __restrict__ x,
                                                   u16* __restrict__ xs) {
  int b = blockIdx.z;
  int cbase = blockIdx.y * 64, nbase = blockIdx.x * 64;
  int tid = threadIdx.x;
  int c_l = tid >> 6, n_l = tid & 63;
  __shared__ __align__(16) u16 tile[64 * 72];
  float v[16];
#pragma unroll
  for (int i = 0; i < 16; ++i) v[i] = 0.f;
  for (int t = 0; t < 4; ++t) {
    const float* xp = x + ((size_t)(t * 16 + b) * 512 + cbase + c_l * 16) * 1024 + nbase + n_l;
#pragma unroll
    for (int i = 0; i < 16; ++i) {
      float xv = xp[(size_t)i * 1024];
      float vn = v[i] + 0.5f * (xv - v[i]);   // v + (x-v)/TAU, TAU=2 (bit-exact vs np)
      bool s = vn >= 1.0f;
      tile[n_l * 72 + c_l * 16 + i] = s ? 0x3F80 : 0;
      v[i] = s ? 0.f : vn;
    }
    __syncthreads();
    u16* yb = xs + ((size_t)(t * 16 + b) * 1024 + nbase) * 512 + cbase;
#pragma unroll
    for (int e = 0; e < 2; ++e) {
      int chunk = tid * 2 + e;
      int n = chunk >> 3, c0 = (chunk & 7) * 8;
      *(uint4*)&yb[(size_t)n * 512 + c0] = *(const uint4*)&tile[n * 72 + c0];
    }
    __syncthreads();
  }
}

// =====================================================================
// gemm_q: fused conv_q + BN + LIF + head-sum + attn-LIF.
// Tile BM=64 x BN=128, 256 thr (4 n-waves, per-wave 64x32 out), 32 KB LDS,
// 4 blocks/CU (grid 1024 = exactly 4/CU): cross-block TLP hides the
// stage->drain latency of the simple 2-barrier K-loop.
// K-loop: hi/lo weight halves interleaved per 64-chunk, B staged once.
// =====================================================================
__global__ __launch_bounds__(256, 4) void gemm_q_kernel(
    const u16* __restrict__ A, const u16* __restrict__ Bbase,
    const float* __restrict__ consts, float* __restrict__ dout) {
  const int tid = threadIdx.x;
  const int lane = tid & 63, w = tid >> 6;       // w = n-wave id 0..3
  const int quad = lane >> 4, l16 = lane & 15;
  const int b = blockIdx.z;
  const int m_blk = blockIdx.y * 64, n_blk = blockIdx.x * 128;
  const int srow = lane >> 3;
  const int scol = (((lane & 7) ^ srow) & 7) * 8;
  __shared__ __align__(16) u16 smem[2 * 4096 + 8192];  // Ash | Asl | Bs (32 KB)
  u16* Ash = smem;
  u16* Asl = smem + 4096;
  u16* Bs  = smem + 8192;
  const int rxor = l16 & 7;
  float v[32];  // LIF state, [ti*2+tj]*4+r
#pragma unroll
  for (int i = 0; i < 32; ++i) v[i] = 0.f;
  float va[2] = {0.f, 0.f};  // attn LIF state per tj

  for (int t = 0; t < 4; ++t) {
    f32x4 acc[4][2];
    const f32x4 zero = {0.f, 0.f, 0.f, 0.f};
#pragma unroll
    for (int i = 0; i < 4; ++i)
#pragma unroll
      for (int j = 0; j < 2; ++j) acc[i][j] = zero;
    const u16* Bt = Bbase + (size_t)(t * 16 + b) * (N_ * C_);

    for (int k0 = 0; k0 < 512; k0 += 64) {
#pragma unroll
      for (int i = 0; i < 2; ++i) {
        int r = i * 32 + w * 8 + srow;
        int lo = (i * 32 + w * 8) * 64;
        async16(A + (size_t)(m_blk + r) * 1024 + k0 + scol, &Ash[lo]);
        async16(A + (size_t)(m_blk + r) * 1024 + 512 + k0 + scol, &Asl[lo]);
      }
#pragma unroll
      for (int i = 0; i < 4; ++i) {
        int r = i * 32 + w * 8 + srow;
        async16(Bt + (size_t)(n_blk + r) * 512 + k0 + scol, &Bs[(i * 32 + w * 8) * 64]);
      }
      __syncthreads();
#pragma unroll
      for (int kk = 0; kk < 2; ++kk) {
        s16x8 ah[4], al[4], bf[2];
        const int slot = ((kk * 4 + quad) ^ rxor) * 8;
#pragma unroll
        for (int ti = 0; ti < 4; ++ti) {
          ah[ti] = *(const s16x8*)&Ash[(ti * 16 + l16) * 64 + slot];
          al[ti] = *(const s16x8*)&Asl[(ti * 16 + l16) * 64 + slot];
        }
#pragma unroll
        for (int tj = 0; tj < 2; ++tj)
          bf[tj] = *(const s16x8*)&Bs[(w * 32 + tj * 16 + l16) * 64 + slot];
#pragma unroll
        for (int ti = 0; ti < 4; ++ti)
#pragma unroll
          for (int tj = 0; tj < 2; ++tj) {
            acc[ti][tj] = __builtin_amdgcn_mfma_f32_16x16x32_bf16(ah[ti], bf[tj], acc[ti][tj], 0, 0, 0);
            acc[ti][tj] = __builtin_amdgcn_mfma_f32_16x16x32_bf16(al[ti], bf[tj], acc[ti][tj], 0, 0, 0);
          }
      }
      __syncthreads();
    }

    // epilogue: BN + LIF + head partial sums (block covers exactly one head)
    float qp[2] = {0.f, 0.f};
#pragma unroll
    for (int ti = 0; ti < 4; ++ti) {
#pragma unroll
      for (int r = 0; r < 4; ++r) {
        int row = m_blk + ti * 16 + quad * 4 + r;
        float iv = consts[row], ib = consts[512 + row];
#pragma unroll
        for (int tj = 0; tj < 2; ++tj) {
          float bnv = acc[ti][tj][r] * iv + ib;
          float vv = v[(ti * 2 + tj) * 4 + r];
          float vn = vv + 0.5f * (bnv - vv);
          bool s = vn >= 1.0f;
          v[(ti * 2 + tj) * 4 + r] = s ? 0.f : vn;
          qp[tj] += s ? 1.f : 0.f;
        }
      }
    }
    int h = m_blk >> 6;
#pragma unroll
    for (int tj = 0; tj < 2; ++tj) {
      float q = qp[tj];
      q += __shfl_xor(q, 16, 64);
      q += __shfl_xor(q, 32, 64);  // sum over quad -> full 64-channel head sum
      float vn = va[tj] + 0.5f * (q - va[tj]);  // exact dyadic
      bool s = vn >= 0.5f;
      va[tj] = s ? 0.f : vn;
      if (quad == 0) {
        int col = n_blk + w * 32 + tj * 16 + l16;
        dout[(size_t)YSZ + ((size_t)(t * 16 + b) * 8 + h) * 1024 + col] = s ? 1.f : 0.f;
      }
    }
  }
}

// =====================================================================
// gemm_k: fused conv_k + BN + LIF + (spike * attn) -> y[t,b,n,c] bf16.
// Same 64x128 tile / 4 blocks-per-CU structure. Transpose via LDS tile
// aliased onto the staging buffers (dead after K-loop), stride 68 u16.
// =====================================================================
__global__ __launch_bounds__(256, 4) void gemm_k_kernel(
    const u16* __restrict__ A, const u16* __restrict__ Bbase,
    const float* __restrict__ consts, const float* __restrict__ dout,
    u16* __restrict__ y) {
  const int tid = threadIdx.x;
  const int lane = tid & 63, w = tid >> 6;
  const int quad = lane >> 4, l16 = lane & 15;
  const int b = blockIdx.z;
  const int m_blk = blockIdx.y * 64, n_blk = blockIdx.x * 128;
  const int srow = lane >> 3;
  const int scol = (((lane & 7) ^ srow) & 7) * 8;
  __shared__ __align__(16) u16 smem[2 * 4096 + 8192];  // Ash | Asl | Bs ; Ys in epilogue
  u16* Ash = smem;
  u16* Asl = smem + 4096;
  u16* Bs  = smem + 8192;
  u16* Ys  = smem;  // 128 x 68 u16 (17.4 KB), aliases staging (dead after K-loop)
  const int rxor = l16 & 7;
  float v[32];
#pragma unroll
  for (int i = 0; i < 32; ++i) v[i] = 0.f;

  for (int t = 0; t < 4; ++t) {
    f32x4 acc[4][2];
    const f32x4 zero = {0.f, 0.f, 0.f, 0.f};
#pragma unroll
    for (int i = 0; i < 4; ++i)
#pragma unroll
      for (int j = 0; j < 2; ++j) acc[i][j] = zero;
    const u16* Bt = Bbase + (size_t)(t * 16 + b) * (N_ * C_);

    for (int k0 = 0; k0 < 512; k0 += 64) {
#pragma unroll
      for (int i = 0; i < 2; ++i) {
        int r = i * 32 + w * 8 + srow;
        int lo = (i * 32 + w * 8) * 64;
        async16(A + (size_t)(m_blk + r) * 1024 + k0 + scol, &Ash[lo]);
        async16(A + (size_t)(m_blk + r) * 1024 + 512 + k0 + scol, &Asl[lo]);
      }
#pragma unroll
      for (int i = 0; i < 4; ++i) {
        int r = i * 32 + w * 8 + srow;
        async16(Bt + (size_t)(n_blk + r) * 512 + k0 + scol, &Bs[(i * 32 + w * 8) * 64]);
      }
      __syncthreads();
#pragma unroll
      for (int kk = 0; kk < 2; ++kk) {
        s16x8 ah[4], al[4], bf[2];
        const int slot = ((kk * 4 + quad) ^ rxor) * 8;
#pragma unroll
        for (int ti = 0; ti < 4; ++ti) {
          ah[ti] = *(const s16x8*)&Ash[(ti * 16 + l16) * 64 + slot];
          al[ti] = *(const s16x8*)&Asl[(ti * 16 + l16) * 64 + slot];
        }
#pragma unroll
        for (int tj = 0; tj < 2; ++tj)
          bf[tj] = *(const s16x8*)&Bs[(w * 32 + tj * 16 + l16) * 64 + slot];
#pragma unroll
        for (int ti = 0; ti < 4; ++ti)
#pragma unroll
          for (int tj = 0; tj < 2; ++tj) {
            acc[ti][tj] = __builtin_amdgcn_mfma_f32_16x16x32_bf16(ah[ti], bf[tj], acc[ti][tj], 0, 0, 0);
            acc[ti][tj] = __builtin_amdgcn_mfma_f32_16x16x32_bf16(al[ti], bf[tj], acc[ti][tj], 0, 0, 0);
          }
      }
      __syncthreads();
    }

    // attn for this block's head/cols (head = m_blk>>6, written by gemm_q)
    int h = m_blk >> 6;
    float at[2];
#pragma unroll
    for (int tj = 0; tj < 2; ++tj) {
      int col = n_blk + w * 32 + tj * 16 + l16;
      at[tj] = dout[(size_t)YSZ + ((size_t)(t * 16 + b) * 8 + h) * 1024 + col];
    }

    // epilogue: BN + LIF + mask, pack 4 consecutive c into LDS transpose tile
#pragma unroll
    for (int ti = 0; ti < 4; ++ti) {
      u16 pk[2][4];
#pragma unroll
      for (int r = 0; r < 4; ++r) {
        int row = m_blk + ti * 16 + quad * 4 + r;
        float iv = consts[1024 + row], ib = consts[1536 + row];
#pragma unroll
        for (int tj = 0; tj < 2; ++tj) {
          float bnv = acc[ti][tj][r] * iv + ib;
          float vv = v[(ti * 2 + tj) * 4 + r];
          float vn = vv + 0.5f * (bnv - vv);
          bool s = vn >= 1.0f;
          v[(ti * 2 + tj) * 4 + r] = s ? 0.f : vn;
          pk[tj][r] = (s && at[tj] != 0.f) ? 0x3F80 : 0;
        }
      }
#pragma unroll
      for (int tj = 0; tj < 2; ++tj) {
        int n_loc = w * 32 + tj * 16 + l16;
        int c_loc = ti * 16 + quad * 4;
        u32 lo2 = (u32)pk[tj][0] | ((u32)pk[tj][1] << 16);
        u32 hi2 = (u32)pk[tj][2] | ((u32)pk[tj][3] << 16);
        uint2 pv2; pv2.x = lo2; pv2.y = hi2;
        *(uint2*)&Ys[n_loc * 68 + c_loc] = pv2;
      }
    }
    __syncthreads();
    // coop store: 128 rows(n) x 64 u16(c) = 128B/row coalesced
    u16* yb = y + ((size_t)(t * 16 + b) * 1024 + n_blk) * 512 + m_blk;
#pragma unroll
    for (int p = 0; p < 4; ++p) {
      int idx = p * 256 + tid;
      int rown = idx >> 3, ch = (idx & 7) * 8;
      *(uint4*)&yb[(size_t)rown * 512 + ch] = *(const uint4*)&Ys[rown * 68 + ch];
    }
    __syncthreads();  // Ys dead before next t's staging overwrites smem
  }
}

// =====================================================================
// gemm_proj: out[d,n] = (sum_k pw[d,k]*y[n,k] + proj_b)*p_inv + p_bias.
// =====================================================================
__global__ __launch_bounds__(256, 3) void gemm_proj_kernel(
    const u16* __restrict__ A, const u16* __restrict__ Bbase,
    float* __restrict__ outP, const float* __restrict__ projb,
    const float* __restrict__ consts) {
  const int tid = threadIdx.x;
  const int lane = tid & 63, w = tid >> 6;
  const int wm = w >> 1, wn = w & 1;
  const int quad = lane >> 4, l16 = lane & 15;
  const int tb = blockIdx.z;
  const int m_blk = blockIdx.y * 128, n_blk = blockIdx.x * 128;
  const int srow = lane >> 3;
  const int scol = (((lane & 7) ^ srow) & 7) * 8;
  __shared__ __align__(16) u16 As[128 * 64];
  __shared__ __align__(16) u16 Bs[128 * 64];
  f32x4 acc[4][4];
  const f32x4 zero = {0.f, 0.f, 0.f, 0.f};
#pragma unroll
  for (int i = 0; i < 4; ++i)
#pragma unroll
    for (int j = 0; j < 4; ++j) acc[i][j] = zero;
  const u16* Bt = Bbase + (size_t)tb * (N_ * C_);
  const int rxor = l16 & 7;

  for (int k0 = 0; k0 < 512; k0 += 64) {
#pragma unroll
    for (int i = 0; i < 4; ++i) {
      int r = i * 32 + w * 8 + srow;
      async16(A + (size_t)(m_blk + r) * 512 + k0 + scol, &As[(i * 32 + w * 8) * 64]);
      async16(Bt + (size_t)(n_blk + r) * 512 + k0 + scol, &Bs[(i * 32 + w * 8) * 64]);
    }
    __syncthreads();
#pragma unroll
    for (int kk = 0; kk < 2; ++kk) {
      s16x8 af[4], bf[4];
      const int slot = ((kk * 4 + quad) ^ rxor) * 8;
#pragma unroll
      for (int ti = 0; ti < 4; ++ti)
        af[ti] = *(const s16x8*)&As[(wm * 64 + ti * 16 + l16) * 64 + slot];
#pragma unroll
      for (int tj = 0; tj < 4; ++tj)
        bf[tj] = *(const s16x8*)&Bs[(wn * 64 + tj * 16 + l16) * 64 + slot];
#pragma unroll
      for (int ti = 0; ti < 4; ++ti)
#pragma unroll
        for (int tj = 0; tj < 4; ++tj)
          acc[ti][tj] = __builtin_amdgcn_mfma_f32_16x16x32_bf16(af[ti], bf[tj], acc[ti][tj], 0, 0, 0);
    }
    __syncthreads();
  }

  const float* pinv = consts + 2048;
  const float* pb2 = consts + 2560;
  float* o = outP + (size_t)tb * (C_ * N_);
#pragma unroll
  for (int ti = 0; ti < 4; ++ti) {
    int row0 = m_blk + wm * 64 + ti * 16 + quad * 4;
#pragma unroll
    for (int r = 0; r < 4; ++r) {
      int row = row0 + r;
      float bi = projb[row], piv = pinv[row], pbi = pb2[row];
#pragma unroll
      for (int tj = 0; tj < 4; ++tj) {
        int col = n_blk + wn * 64 + tj * 16 + l16;
        o[(size_t)row * N_ + col] = (acc[ti][tj][r] + bi) * piv + pbi;
      }
    }
  }
}

// =====================================================================
extern "C" void kernel_launch(void* const* d_in, const int* in_sizes, int n_in,
                              void* d_out, int out_size, void* d_ws, size_t ws_size,
                              hipStream_t stream) {
  const float* x   = (const float*)d_in[0];
  const float* qw  = (const float*)d_in[1];
  const float* qg  = (const float*)d_in[2];
  const float* qb  = (const float*)d_in[3];
  const float* qm  = (const float*)d_in[4];
  const float* qv  = (const float*)d_in[5];
  const float* kw  = (const float*)d_in[6];
  const float* kg  = (const float*)d_in[7];
  const float* kb  = (const float*)d_in[8];
  const float* km  = (const float*)d_in[9];
  const float* kv  = (const float*)d_in[10];
  const float* pw  = (const float*)d_in[11];
  const float* pb  = (const float*)d_in[12];
  const float* pg  = (const float*)d_in[13];
  const float* pbt = (const float*)d_in[14];
  const float* pm  = (const float*)d_in[15];
  const float* pv  = (const float*)d_in[16];
  float* out = (float*)d_out;
  char* ws = (char*)d_ws;

  u16* xs       = (u16*)ws;                    // 64 MB spikes [t,b,n,c]
  u16* y2       = (u16*)(ws + 67108864);       // 64 MB y [t,b,n,c]
  u16* whlq     = (u16*)(ws + 201326592);
  u16* whlk     = (u16*)(ws + 202375168);
  u16* pwb      = (u16*)(ws + 203423744);
  float* consts = (float*)(ws + 203948032);

  prep_kernel<<<513, 256, 0, stream>>>(qw, kw, pw, qg, qb, qm, qv, kg, kb, km, kv,
                                       pg, pbt, pm, pv, whlq, whlk, pwb, consts);
  lifx_kernel<<<dim3(16, 8, 16), 256, 0, stream>>>(x, xs);
  gemm_q_kernel<<<dim3(8, 8, 16), 256, 0, stream>>>(whlq, xs, consts, out);
  gemm_k_kernel<<<dim3(8, 8, 16), 256, 0, stream>>>(whlk, xs, consts, out, y2);
  gemm_proj_kernel<<<dim3(8, 4, 64), 256, 0, stream>>>(pwb, y2, out, pb, consts);
}

// Round 3
// 467.363 us; speedup vs baseline: 1.0874x; 1.0168x over previous
//
#include <hip/hip_runtime.h>

typedef unsigned char u8;
typedef unsigned short u16;
typedef unsigned int u32;
typedef float f32x4 __attribute__((ext_vector_type(4)));
typedef short s16x8 __attribute__((ext_vector_type(8)));

#define T_ 4
#define B_ 16
#define C_ 512
#define N_ 1024
#define YSZ 33554432  // 64*512*1024 (y output elements); attn follows in d_out

// ---- bf16 helpers (manual RNE) ----
__device__ __forceinline__ u16 f2bf(float f) {
  u32 u = __float_as_uint(f);
  u32 r = u + 0x7FFFu + ((u >> 16) & 1u);
  return (u16)(r >> 16);
}
__device__ __forceinline__ float bf2f(u16 h) { return __uint_as_float(((u32)h) << 16); }

// ---- async global->LDS, 16B per lane, wave-uniform LDS base ----
__device__ __forceinline__ void async16(const void* g, void* l) {
  __builtin_amdgcn_global_load_lds((const __attribute__((address_space(1))) void*)g,
                                   (__attribute__((address_space(3))) void*)l, 16, 0, 0);
}

// ---- expand 8 spike bits -> 8 bf16 {0,1.0} (s16x8 MFMA operand) ----
__device__ __forceinline__ s16x8 expand8(u32 m) {
  union { u32 w[4]; s16x8 v; } u;
  u.w[0] = (m & 1u   ? 0x3F80u : 0u) | (m & 2u   ? 0x3F800000u : 0u);
  u.w[1] = (m & 4u   ? 0x3F80u : 0u) | (m & 8u   ? 0x3F800000u : 0u);
  u.w[2] = (m & 16u  ? 0x3F80u : 0u) | (m & 32u  ? 0x3F800000u : 0u);
  u.w[3] = (m & 64u  ? 0x3F80u : 0u) | (m & 128u ? 0x3F800000u : 0u);
  return u.v;
}

// =====================================================================
// prep: split q_w/k_w into bf16 hi|lo concat [512][1024]; proj_w -> bf16;
//       BN constants (inv, bias) for q/k/p into consts[].
// =====================================================================
__global__ void prep_kernel(const float* __restrict__ qw, const float* __restrict__ kw,
                            const float* __restrict__ pw,
                            const float* __restrict__ qg, const float* __restrict__ qb,
                            const float* __restrict__ qm, const float* __restrict__ qv,
                            const float* __restrict__ kg, const float* __restrict__ kb,
                            const float* __restrict__ km, const float* __restrict__ kv,
                            const float* __restrict__ pg, const float* __restrict__ pbt,
                            const float* __restrict__ pm, const float* __restrict__ pv,
                            u16* __restrict__ whlq, u16* __restrict__ whlk,
                            u16* __restrict__ pwb, float* __restrict__ consts) {
  int blk = blockIdx.x, tid = threadIdx.x;
  if (blk < 512) {
    int d = blk;
    for (int c = tid; c < 512; c += 256) {
      float w = qw[d * 512 + c];
      u16 hi = f2bf(w);
      whlq[d * 1024 + c] = hi;
      whlq[d * 1024 + 512 + c] = f2bf(w - bf2f(hi));
      w = kw[d * 512 + c];
      hi = f2bf(w);
      whlk[d * 1024 + c] = hi;
      whlk[d * 1024 + 512 + c] = f2bf(w - bf2f(hi));
      pwb[d * 512 + c] = f2bf(pw[d * 512 + c]);
    }
  } else {
    for (int c = tid; c < 512; c += 256) {
      float inv = qg[c] / sqrtf(qv[c] + 1e-5f);
      consts[c] = inv; consts[512 + c] = qb[c] - qm[c] * inv;
      inv = kg[c] / sqrtf(kv[c] + 1e-5f);
      consts[1024 + c] = inv; consts[1536 + c] = kb[c] - km[c] * inv;
      inv = pg[c] / sqrtf(pv[c] + 1e-5f);
      consts[2048 + c] = inv; consts[2560 + c] = pbt[c] - pm[c] * inv;
    }
  }
}

// =====================================================================
// lif_x: x[t,b,c,n] f32 -> bitpacked spikes xsb[t,b,n, 64B of c-bits].
// bit j of byte cb  <->  c = cb*8 + j.  No LDS needed.
// =====================================================================
__global__ __launch_bounds__(256) void lifx_kernel(const float* __restrict__ x,
                                                   u8* __restrict__ xsb) {
  int b = blockIdx.z;
  int cbase = blockIdx.y * 64, nbase = blockIdx.x * 64;
  int tid = threadIdx.x;
  int c_l = tid >> 6, n_l = tid & 63;   // c_l: which 16-channel group; n_l: spatial row
  float v[16];
#pragma unroll
  for (int i = 0; i < 16; ++i) v[i] = 0.f;
  for (int t = 0; t < 4; ++t) {
    const float* xp = x + ((size_t)(t * 16 + b) * 512 + cbase + c_l * 16) * 1024 + nbase + n_l;
    u32 mask = 0;
#pragma unroll
    for (int i = 0; i < 16; ++i) {
      float xv = xp[(size_t)i * 1024];
      float vn = v[i] + 0.5f * (xv - v[i]);   // v + (x-v)/TAU, TAU=2 (bit-exact vs np)
      bool s = vn >= 1.0f;
      mask |= (s ? 1u : 0u) << i;
      v[i] = s ? 0.f : vn;
    }
    *(u16*)&xsb[((size_t)(t * 16 + b) * 1024 + nbase + n_l) * 64 + (cbase >> 3) + c_l * 2] =
        (u16)mask;
  }
}

// =====================================================================
// gemm_q: fused conv_q + BN + LIF + head-sum + attn-LIF.
// BM=64 x BN=128, 4 n-waves, 4 blocks/CU. A (weights hi/lo) staged in LDS
// (16 KB/K-step); B (spikes) loaded as BITS straight from global into
// registers (8B/lane/K-step, L1-resident) and expanded to bf16 in-register.
// Numerics identical to the bf16-staged version (values are {0,1.0bf16}).
// =====================================================================
__global__ __launch_bounds__(256, 4) void gemm_q_kernel(
    const u16* __restrict__ A, const u8* __restrict__ xsb,
    const float* __restrict__ consts, float* __restrict__ dout) {
  const int tid = threadIdx.x;
  const int lane = tid & 63, w = tid >> 6;       // w = n-wave id 0..3
  const int quad = lane >> 4, l16 = lane & 15;
  const int b = blockIdx.z;
  const int m_blk = blockIdx.y * 64, n_blk = blockIdx.x * 128;
  const int srow = lane >> 3;
  const int scol = (((lane & 7) ^ srow) & 7) * 8;
  __shared__ __align__(16) u16 smem[2 * 4096];   // Ash | Asl (16 KB)
  u16* Ash = smem;
  u16* Asl = smem + 4096;
  const int rxor = l16 & 7;
  // bit rows for this lane's two B-fragments (n-local = w*32 + tj*16 + l16)
  const int row0 = n_blk + w * 32 + l16;
  const int row1 = row0 + 16;
  float v[32];  // LIF state, [ti*2+tj]*4+r
#pragma unroll
  for (int i = 0; i < 32; ++i) v[i] = 0.f;
  float va[2] = {0.f, 0.f};  // attn LIF state per tj

  for (int t = 0; t < 4; ++t) {
    f32x4 acc[4][2];
    const f32x4 zero = {0.f, 0.f, 0.f, 0.f};
#pragma unroll
    for (int i = 0; i < 4; ++i)
#pragma unroll
      for (int j = 0; j < 2; ++j) acc[i][j] = zero;
    const u8* bitsT = xsb + (size_t)(t * 16 + b) * (N_ * 64);

    for (int k0 = 0; k0 < 512; k0 += 64) {
#pragma unroll
      for (int i = 0; i < 2; ++i) {
        int r = i * 32 + w * 8 + srow;
        int lo = (i * 32 + w * 8) * 64;
        async16(A + (size_t)(m_blk + r) * 1024 + k0 + scol, &Ash[lo]);
        async16(A + (size_t)(m_blk + r) * 1024 + 512 + k0 + scol, &Asl[lo]);
      }
      // B bits: 8 bytes per row for this K-chunk (independent of LDS staging)
      uint2 g0 = *(const uint2*)&bitsT[(size_t)row0 * 64 + (k0 >> 3)];
      uint2 g1 = *(const uint2*)&bitsT[(size_t)row1 * 64 + (k0 >> 3)];
      __syncthreads();
#pragma unroll
      for (int kk = 0; kk < 2; ++kk) {
        s16x8 ah[4], al[4], bf[2];
        const int slot = ((kk * 4 + quad) ^ rxor) * 8;
#pragma unroll
        for (int ti = 0; ti < 4; ++ti) {
          ah[ti] = *(const s16x8*)&Ash[(ti * 16 + l16) * 64 + slot];
          al[ti] = *(const s16x8*)&Asl[(ti * 16 + l16) * 64 + slot];
        }
        u32 w0 = kk ? g0.y : g0.x;
        u32 w1 = kk ? g1.y : g1.x;
        bf[0] = expand8((w0 >> (quad * 8)) & 0xFFu);
        bf[1] = expand8((w1 >> (quad * 8)) & 0xFFu);
#pragma unroll
        for (int ti = 0; ti < 4; ++ti)
#pragma unroll
          for (int tj = 0; tj < 2; ++tj) {
            acc[ti][tj] = __builtin_amdgcn_mfma_f32_16x16x32_bf16(ah[ti], bf[tj], acc[ti][tj], 0, 0, 0);
            acc[ti][tj] = __builtin_amdgcn_mfma_f32_16x16x32_bf16(al[ti], bf[tj], acc[ti][tj], 0, 0, 0);
          }
      }
      __syncthreads();
    }

    // epilogue: BN + LIF + head partial sums (block covers exactly one head)
    float qp[2] = {0.f, 0.f};
#pragma unroll
    for (int ti = 0; ti < 4; ++ti) {
#pragma unroll
      for (int r = 0; r < 4; ++r) {
        int row = m_blk + ti * 16 + quad * 4 + r;
        float iv = consts[row], ib = consts[512 + row];
#pragma unroll
        for (int tj = 0; tj < 2; ++tj) {
          float bnv = acc[ti][tj][r] * iv + ib;
          float vv = v[(ti * 2 + tj) * 4 + r];
          float vn = vv + 0.5f * (bnv - vv);
          bool s = vn >= 1.0f;
          v[(ti * 2 + tj) * 4 + r] = s ? 0.f : vn;
          qp[tj] += s ? 1.f : 0.f;
        }
      }
    }
    int h = m_blk >> 6;
#pragma unroll
    for (int tj = 0; tj < 2; ++tj) {
      float q = qp[tj];
      q += __shfl_xor(q, 16, 64);
      q += __shfl_xor(q, 32, 64);  // sum over quad -> full 64-channel head sum
      float vn = va[tj] + 0.5f * (q - va[tj]);  // exact dyadic
      bool s = vn >= 0.5f;
      va[tj] = s ? 0.f : vn;
      if (quad == 0) {
        int col = n_blk + w * 32 + tj * 16 + l16;
        dout[(size_t)YSZ + ((size_t)(t * 16 + b) * 8 + h) * 1024 + col] = s ? 1.f : 0.f;
      }
    }
  }
}

// =====================================================================
// gemm_k: fused conv_k + BN + LIF + (spike * attn) -> y2b bitpacked
// [t,b,n, 64B of c-bits].  Same reg-direct B-bits main loop as gemm_q.
// Transpose via LDS tile (stride 72 u16) aliased onto staging, then
// bitpack on the coop store (1 KB out per block-t instead of 16 KB).
// =====================================================================
__global__ __launch_bounds__(256, 4) void gemm_k_kernel(
    const u16* __restrict__ A, const u8* __restrict__ xsb,
    const float* __restrict__ consts, const float* __restrict__ dout,
    u8* __restrict__ y2b) {
  const int tid = threadIdx.x;
  const int lane = tid & 63, w = tid >> 6;
  const int quad = lane >> 4, l16 = lane & 15;
  const int b = blockIdx.z;
  const int m_blk = blockIdx.y * 64, n_blk = blockIdx.x * 128;
  const int srow = lane >> 3;
  const int scol = (((lane & 7) ^ srow) & 7) * 8;
  __shared__ __align__(16) u16 smem[9216];  // Ash|Asl (16 KB) ; Ys 128x72 (18 KB) aliased
  u16* Ash = smem;
  u16* Asl = smem + 4096;
  u16* Ys  = smem;  // stride 72 u16 (16B-aligned uint4 rows)
  const int rxor = l16 & 7;
  const int row0 = n_blk + w * 32 + l16;
  const int row1 = row0 + 16;
  float v[32];
#pragma unroll
  for (int i = 0; i < 32; ++i) v[i] = 0.f;

  for (int t = 0; t < 4; ++t) {
    f32x4 acc[4][2];
    const f32x4 zero = {0.f, 0.f, 0.f, 0.f};
#pragma unroll
    for (int i = 0; i < 4; ++i)
#pragma unroll
      for (int j = 0; j < 2; ++j) acc[i][j] = zero;
    const u8* bitsT = xsb + (size_t)(t * 16 + b) * (N_ * 64);

    for (int k0 = 0; k0 < 512; k0 += 64) {
#pragma unroll
      for (int i = 0; i < 2; ++i) {
        int r = i * 32 + w * 8 + srow;
        int lo = (i * 32 + w * 8) * 64;
        async16(A + (size_t)(m_blk + r) * 1024 + k0 + scol, &Ash[lo]);
        async16(A + (size_t)(m_blk + r) * 1024 + 512 + k0 + scol, &Asl[lo]);
      }
      uint2 g0 = *(const uint2*)&bitsT[(size_t)row0 * 64 + (k0 >> 3)];
      uint2 g1 = *(const uint2*)&bitsT[(size_t)row1 * 64 + (k0 >> 3)];
      __syncthreads();
#pragma unroll
      for (int kk = 0; kk < 2; ++kk) {
        s16x8 ah[4], al[4], bf[2];
        const int slot = ((kk * 4 + quad) ^ rxor) * 8;
#pragma unroll
        for (int ti = 0; ti < 4; ++ti) {
          ah[ti] = *(const s16x8*)&Ash[(ti * 16 + l16) * 64 + slot];
          al[ti] = *(const s16x8*)&Asl[(ti * 16 + l16) * 64 + slot];
        }
        u32 w0 = kk ? g0.y : g0.x;
        u32 w1 = kk ? g1.y : g1.x;
        bf[0] = expand8((w0 >> (quad * 8)) & 0xFFu);
        bf[1] = expand8((w1 >> (quad * 8)) & 0xFFu);
#pragma unroll
        for (int ti = 0; ti < 4; ++ti)
#pragma unroll
          for (int tj = 0; tj < 2; ++tj) {
            acc[ti][tj] = __builtin_amdgcn_mfma_f32_16x16x32_bf16(ah[ti], bf[tj], acc[ti][tj], 0, 0, 0);
            acc[ti][tj] = __builtin_amdgcn_mfma_f32_16x16x32_bf16(al[ti], bf[tj], acc[ti][tj], 0, 0, 0);
          }
      }
      __syncthreads();
    }

    // attn for this block's head/cols (head = m_blk>>6, written by gemm_q)
    int h = m_blk >> 6;
    float at[2];
#pragma unroll
    for (int tj = 0; tj < 2; ++tj) {
      int col = n_blk + w * 32 + tj * 16 + l16;
      at[tj] = dout[(size_t)YSZ + ((size_t)(t * 16 + b) * 8 + h) * 1024 + col];
    }

    // epilogue: BN + LIF + mask, pack 4 consecutive c into LDS transpose tile
#pragma unroll
    for (int ti = 0; ti < 4; ++ti) {
      u16 pk[2][4];
#pragma unroll
      for (int r = 0; r < 4; ++r) {
        int row = m_blk + ti * 16 + quad * 4 + r;
        float iv = consts[1024 + row], ib = consts[1536 + row];
#pragma unroll
        for (int tj = 0; tj < 2; ++tj) {
          float bnv = acc[ti][tj][r] * iv + ib;
          float vv = v[(ti * 2 + tj) * 4 + r];
          float vn = vv + 0.5f * (bnv - vv);
          bool s = vn >= 1.0f;
          v[(ti * 2 + tj) * 4 + r] = s ? 0.f : vn;
          pk[tj][r] = (s && at[tj] != 0.f) ? 0x3F80 : 0;
        }
      }
#pragma unroll
      for (int tj = 0; tj < 2; ++tj) {
        int n_loc = w * 32 + tj * 16 + l16;
        int c_loc = ti * 16 + quad * 4;
        u32 lo2 = (u32)pk[tj][0] | ((u32)pk[tj][1] << 16);
        u32 hi2 = (u32)pk[tj][2] | ((u32)pk[tj][3] << 16);
        uint2 pv2; pv2.x = lo2; pv2.y = hi2;
        *(uint2*)&Ys[n_loc * 72 + c_loc] = pv2;
      }
    }
    __syncthreads();
    // coop store: bitpack 128 rows(n) x 64 c -> 8 bytes/row
    u8* yb = y2b + ((size_t)(t * 16 + b) * 1024 + n_blk) * 64 + (m_blk >> 3);
#pragma unroll
    for (int p = 0; p < 4; ++p) {
      int idx = p * 256 + tid;
      int rown = idx >> 3, bc = idx & 7;
      uint4 q = *(const uint4*)&Ys[rown * 72 + bc * 8];
      u32 byte = ((q.x >> 7) & 1u) | (((q.x >> 23) & 1u) << 1) |
                 (((q.y >> 7) & 1u) << 2) | (((q.y >> 23) & 1u) << 3) |
                 (((q.z >> 7) & 1u) << 4) | (((q.z >> 23) & 1u) << 5) |
                 (((q.w >> 7) & 1u) << 6) | (((q.w >> 23) & 1u) << 7);
      yb[(size_t)rown * 64 + bc] = (u8)byte;
    }
    __syncthreads();  // Ys dead before next t's staging overwrites smem
  }
}

// =====================================================================
// gemm_proj: out[d,n] = (sum_k pw[d,k]*y[n,k] + proj_b)*p_inv + p_bias.
// B operand (y spikes) from y2b bits, reg-direct + expand (values exactly
// match the previous bf16 y2 path: {0,1.0bf16}).
// =====================================================================
__global__ __launch_bounds__(256, 3) void gemm_proj_kernel(
    const u16* __restrict__ A, const u8* __restrict__ y2b,
    float* __restrict__ outP, const float* __restrict__ projb,
    const float* __restrict__ consts) {
  const int tid = threadIdx.x;
  const int lane = tid & 63, w = tid >> 6;
  const int wm = w >> 1, wn = w & 1;
  const int quad = lane >> 4, l16 = lane & 15;
  const int tb = blockIdx.z;
  const int m_blk = blockIdx.y * 128, n_blk = blockIdx.x * 128;
  const int srow = lane >> 3;
  const int scol = (((lane & 7) ^ srow) & 7) * 8;
  __shared__ __align__(16) u16 As[128 * 64];
  f32x4 acc[4][4];
  const f32x4 zero = {0.f, 0.f, 0.f, 0.f};
#pragma unroll
  for (int i = 0; i < 4; ++i)
#pragma unroll
    for (int j = 0; j < 4; ++j) acc[i][j] = zero;
  const u8* bitsT = y2b + (size_t)tb * (N_ * 64);
  const int rxor = l16 & 7;
  const int browb = n_blk + wn * 64 + l16;

  for (int k0 = 0; k0 < 512; k0 += 64) {
#pragma unroll
    for (int i = 0; i < 4; ++i) {
      int r = i * 32 + w * 8 + srow;
      async16(A + (size_t)(m_blk + r) * 512 + k0 + scol, &As[(i * 32 + w * 8) * 64]);
    }
    uint2 g[4];
#pragma unroll
    for (int tj = 0; tj < 4; ++tj)
      g[tj] = *(const uint2*)&bitsT[(size_t)(browb + tj * 16) * 64 + (k0 >> 3)];
    __syncthreads();
#pragma unroll
    for (int kk = 0; kk < 2; ++kk) {
      s16x8 af[4], bf[4];
      const int slot = ((kk * 4 + quad) ^ rxor) * 8;
#pragma unroll
      for (int ti = 0; ti < 4; ++ti)
        af[ti] = *(const s16x8*)&As[(wm * 64 + ti * 16 + l16) * 64 + slot];
#pragma unroll
      for (int tj = 0; tj < 4; ++tj) {
        u32 wbits = kk ? g[tj].y : g[tj].x;
        bf[tj] = expand8((wbits >> (quad * 8)) & 0xFFu);
      }
#pragma unroll
      for (int ti = 0; ti < 4; ++ti)
#pragma unroll
        for (int tj = 0; tj < 4; ++tj)
          acc[ti][tj] = __builtin_amdgcn_mfma_f32_16x16x32_bf16(af[ti], bf[tj], acc[ti][tj], 0, 0, 0);
    }
    __syncthreads();
  }

  const float* pinv = consts + 2048;
  const float* pb2 = consts + 2560;
  float* o = outP + (size_t)tb * (C_ * N_);
#pragma unroll
  for (int ti = 0; ti < 4; ++ti) {
    int row0 = m_blk + wm * 64 + ti * 16 + quad * 4;
#pragma unroll
    for (int r = 0; r < 4; ++r) {
      int row = row0 + r;
      float bi = projb[row], piv = pinv[row], pbi = pb2[row];
#pragma unroll
      for (int tj = 0; tj < 4; ++tj) {
        int col = n_blk + wn * 64 + tj * 16 + l16;
        o[(size_t)row * N_ + col] = (acc[ti][tj][r] + bi) * piv + pbi;
      }
    }
  }
}

// =====================================================================
extern "C" void kernel_launch(void* const* d_in, const int* in_sizes, int n_in,
                              void* d_out, int out_size, void* d_ws, size_t ws_size,
                              hipStream_t stream) {
  const float* x   = (const float*)d_in[0];
  const float* qw  = (const float*)d_in[1];
  const float* qg  = (const float*)d_in[2];
  const float* qb  = (const float*)d_in[3];
  const float* qm  = (const float*)d_in[4];
  const float* qv  = (const float*)d_in[5];
  const float* kw  = (const float*)d_in[6];
  const float* kg  = (const float*)d_in[7];
  const float* kb  = (const float*)d_in[8];
  const float* km  = (const float*)d_in[9];
  const float* kv  = (const float*)d_in[10];
  const float* pw  = (const float*)d_in[11];
  const float* pb  = (const float*)d_in[12];
  const float* pg  = (const float*)d_in[13];
  const float* pbt = (const float*)d_in[14];
  const float* pm  = (const float*)d_in[15];
  const float* pv  = (const float*)d_in[16];
  float* out = (float*)d_out;
  char* ws = (char*)d_ws;

  u8*  xsb      = (u8*)ws;                     // 4 MB spike bits [t,b,n, 64B]
  u8*  y2b      = (u8*)(ws + 4194304);         // 4 MB y spike bits [t,b,n, 64B]
  u16* whlq     = (u16*)(ws + 8388608);        // 1 MB
  u16* whlk     = (u16*)(ws + 9437184);        // 1 MB
  u16* pwb      = (u16*)(ws + 10485760);       // 512 KB
  float* consts = (float*)(ws + 11010048);     // 12 KB

  prep_kernel<<<513, 256, 0, stream>>>(qw, kw, pw, qg, qb, qm, qv, kg, kb, km, kv,
                                       pg, pbt, pm, pv, whlq, whlk, pwb, consts);
  lifx_kernel<<<dim3(16, 8, 16), 256, 0, stream>>>(x, xsb);
  gemm_q_kernel<<<dim3(8, 8, 16), 256, 0, stream>>>(whlq, xsb, consts, out);
  gemm_k_kernel<<<dim3(8, 8, 16), 256, 0, stream>>>(whlk, xsb, consts, out, y2b);
  gemm_proj_kernel<<<dim3(8, 4, 64), 256, 0, stream>>>(pwb, y2b, out, pb, consts);
}

// Round 4
// 449.551 us; speedup vs baseline: 1.1305x; 1.0396x over previous
//
#include <hip/hip_runtime.h>

typedef unsigned char u8;
typedef unsigned short u16;
typedef unsigned int u32;
typedef float f32x4 __attribute__((ext_vector_type(4)));
typedef short s16x8 __attribute__((ext_vector_type(8)));

#define T_ 4
#define B_ 16
#define C_ 512
#define N_ 1024
#define YSZ 33554432  // 64*512*1024 (y output elements); attn follows in d_out

// ---- bf16 helpers (manual RNE) ----
__device__ __forceinline__ u16 f2bf(float f) {
  u32 u = __float_as_uint(f);
  u32 r = u + 0x7FFFu + ((u >> 16) & 1u);
  return (u16)(r >> 16);
}
__device__ __forceinline__ float bf2f(u16 h) { return __uint_as_float(((u32)h) << 16); }

// ---- async global->LDS, 16B per lane, wave-uniform LDS base ----
__device__ __forceinline__ void async16(const void* g, void* l) {
  __builtin_amdgcn_global_load_lds((const __attribute__((address_space(1))) void*)g,
                                   (__attribute__((address_space(3))) void*)l, 16, 0, 0);
}

// ---- expand 8 spike bits -> 8 bf16 {0,1.0} (s16x8 MFMA operand) ----
__device__ __forceinline__ s16x8 expand8(u32 m) {
  union { u32 w[4]; s16x8 v; } u;
  u.w[0] = (m & 1u   ? 0x3F80u : 0u) | (m & 2u   ? 0x3F800000u : 0u);
  u.w[1] = (m & 4u   ? 0x3F80u : 0u) | (m & 8u   ? 0x3F800000u : 0u);
  u.w[2] = (m & 16u  ? 0x3F80u : 0u) | (m & 32u  ? 0x3F800000u : 0u);
  u.w[3] = (m & 64u  ? 0x3F80u : 0u) | (m & 128u ? 0x3F800000u : 0u);
  return u.v;
}

// =====================================================================
// prep: split q_w/k_w into bf16 hi|lo concat [512][1024]; proj_w -> bf16;
//       BN constants (inv, bias) for q/k/p into consts[].
// =====================================================================
__global__ void prep_kernel(const float* __restrict__ qw, const float* __restrict__ kw,
                            const float* __restrict__ pw,
                            const float* __restrict__ qg, const float* __restrict__ qb,
                            const float* __restrict__ qm, const float* __restrict__ qv,
                            const float* __restrict__ kg, const float* __restrict__ kb,
                            const float* __restrict__ km, const float* __restrict__ kv,
                            const float* __restrict__ pg, const float* __restrict__ pbt,
                            const float* __restrict__ pm, const float* __restrict__ pv,
                            u16* __restrict__ whlq, u16* __restrict__ whlk,
                            u16* __restrict__ pwb, float* __restrict__ consts) {
  int blk = blockIdx.x, tid = threadIdx.x;
  if (blk < 512) {
    int d = blk;
    for (int c = tid; c < 512; c += 256) {
      float w = qw[d * 512 + c];
      u16 hi = f2bf(w);
      whlq[d * 1024 + c] = hi;
      whlq[d * 1024 + 512 + c] = f2bf(w - bf2f(hi));
      w = kw[d * 512 + c];
      hi = f2bf(w);
      whlk[d * 1024 + c] = hi;
      whlk[d * 1024 + 512 + c] = f2bf(w - bf2f(hi));
      pwb[d * 512 + c] = f2bf(pw[d * 512 + c]);
    }
  } else {
    for (int c = tid; c < 512; c += 256) {
      float inv = qg[c] / sqrtf(qv[c] + 1e-5f);
      consts[c] = inv; consts[512 + c] = qb[c] - qm[c] * inv;
      inv = kg[c] / sqrtf(kv[c] + 1e-5f);
      consts[1024 + c] = inv; consts[1536 + c] = kb[c] - km[c] * inv;
      inv = pg[c] / sqrtf(pv[c] + 1e-5f);
      consts[2048 + c] = inv; consts[2560 + c] = pbt[c] - pm[c] * inv;
    }
  }
}

// =====================================================================
// lif_x: x[t,b,c,n] f32 -> bitpacked spikes xsb[t,b,n, 64B of c-bits].
// bit j of byte cb  <->  c = cb*8 + j.  No LDS needed.
// =====================================================================
__global__ __launch_bounds__(256) void lifx_kernel(const float* __restrict__ x,
                                                   u8* __restrict__ xsb) {
  int b = blockIdx.z;
  int cbase = blockIdx.y * 64, nbase = blockIdx.x * 64;
  int tid = threadIdx.x;
  int c_l = tid >> 6, n_l = tid & 63;   // c_l: which 16-channel group; n_l: spatial row
  float v[16];
#pragma unroll
  for (int i = 0; i < 16; ++i) v[i] = 0.f;
  for (int t = 0; t < 4; ++t) {
    const float* xp = x + ((size_t)(t * 16 + b) * 512 + cbase + c_l * 16) * 1024 + nbase + n_l;
    u32 mask = 0;
#pragma unroll
    for (int i = 0; i < 16; ++i) {
      float xv = xp[(size_t)i * 1024];
      float vn = v[i] + 0.5f * (xv - v[i]);   // v + (x-v)/TAU, TAU=2 (bit-exact vs np)
      bool s = vn >= 1.0f;
      mask |= (s ? 1u : 0u) << i;
      v[i] = s ? 0.f : vn;
    }
    *(u16*)&xsb[((size_t)(t * 16 + b) * 1024 + nbase + n_l) * 64 + (cbase >> 3) + c_l * 2] =
        (u16)mask;
  }
}

// =====================================================================
// gemm_q: fused conv_q + BN + LIF + head-sum + attn-LIF.
// BASELINE r0 geometry: BM=128 x BN=128, 4 waves (2m x 2n), 64 MFMA per
// K-step per wave, 2-barrier loop, 2 blocks/CU. Only change vs r0: the
// B operand comes from bitpacked spikes loaded global->reg (8 B/lane/step,
// L1-resident) and expanded in-register to {0,1.0}bf16 -- operand values
// bit-identical to the bf16-staged version, MFMA order unchanged.
// A staging drops to 32 KB/step (was 48 KB with the B tile).
// =====================================================================
__global__ __launch_bounds__(256, 2) void gemm_q_kernel(
    const u16* __restrict__ A, const u8* __restrict__ xsb,
    const float* __restrict__ consts, float* __restrict__ dout) {
  const int tid = threadIdx.x;
  const int lane = tid & 63, w = tid >> 6;
  const int wm = w >> 1, wn = w & 1;
  const int quad = lane >> 4, l16 = lane & 15;
  const int b = blockIdx.z;
  const int m_blk = blockIdx.y * 128, n_blk = blockIdx.x * 128;
  const int srow = lane >> 3;
  const int scol = (((lane & 7) ^ srow) & 7) * 8;
  __shared__ __align__(16) u16 smem[2 * 8192];  // Ash | Asl (32 KB)
  u16* Ash = smem;
  u16* Asl = smem + 8192;
  const int rxor = l16 & 7;
  const int brow = n_blk + wn * 64 + l16;  // + tj*16 -> bit row per fragment
  float v[64];  // LIF state, [ti*4+tj]*4+r
#pragma unroll
  for (int i = 0; i < 64; ++i) v[i] = 0.f;
  float va[4] = {0.f, 0.f, 0.f, 0.f};  // attn LIF state per tj

  for (int t = 0; t < 4; ++t) {
    f32x4 acc[4][4];
    const f32x4 zero = {0.f, 0.f, 0.f, 0.f};
#pragma unroll
    for (int i = 0; i < 4; ++i)
#pragma unroll
      for (int j = 0; j < 4; ++j) acc[i][j] = zero;
    const u8* bitsT = xsb + (size_t)(t * 16 + b) * (N_ * 64);

    for (int k0 = 0; k0 < 512; k0 += 64) {
#pragma unroll
      for (int i = 0; i < 4; ++i) {
        int r = i * 32 + w * 8 + srow;
        int lo = (i * 32 + w * 8) * 64;
        async16(A + (size_t)(m_blk + r) * 1024 + k0 + scol, &Ash[lo]);
        async16(A + (size_t)(m_blk + r) * 1024 + 512 + k0 + scol, &Asl[lo]);
      }
      uint2 g[4];  // B bits: 8 B per fragment row for this K-chunk
#pragma unroll
      for (int tj = 0; tj < 4; ++tj)
        g[tj] = *(const uint2*)&bitsT[(size_t)(brow + tj * 16) * 64 + (k0 >> 3)];
      __syncthreads();
#pragma unroll
      for (int kk = 0; kk < 2; ++kk) {
        s16x8 ah[4], al[4], bf[4];
        const int slot = ((kk * 4 + quad) ^ rxor) * 8;
#pragma unroll
        for (int ti = 0; ti < 4; ++ti) {
          ah[ti] = *(const s16x8*)&Ash[(wm * 64 + ti * 16 + l16) * 64 + slot];
          al[ti] = *(const s16x8*)&Asl[(wm * 64 + ti * 16 + l16) * 64 + slot];
        }
#pragma unroll
        for (int tj = 0; tj < 4; ++tj) {
          u32 wb = kk ? g[tj].y : g[tj].x;
          bf[tj] = expand8((wb >> (quad * 8)) & 0xFFu);
        }
#pragma unroll
        for (int ti = 0; ti < 4; ++ti)
#pragma unroll
          for (int tj = 0; tj < 4; ++tj) {
            acc[ti][tj] = __builtin_amdgcn_mfma_f32_16x16x32_bf16(ah[ti], bf[tj], acc[ti][tj], 0, 0, 0);
            acc[ti][tj] = __builtin_amdgcn_mfma_f32_16x16x32_bf16(al[ti], bf[tj], acc[ti][tj], 0, 0, 0);
          }
      }
      __syncthreads();
    }

    // epilogue: BN + LIF + head partial sums
    float qp[4] = {0.f, 0.f, 0.f, 0.f};
#pragma unroll
    for (int ti = 0; ti < 4; ++ti) {
#pragma unroll
      for (int r = 0; r < 4; ++r) {
        int row = m_blk + wm * 64 + ti * 16 + quad * 4 + r;
        float iv = consts[row], ib = consts[512 + row];
#pragma unroll
        for (int tj = 0; tj < 4; ++tj) {
          float bnv = acc[ti][tj][r] * iv + ib;
          float vv = v[(ti * 4 + tj) * 4 + r];
          float vn = vv + 0.5f * (bnv - vv);
          bool s = vn >= 1.0f;
          v[(ti * 4 + tj) * 4 + r] = s ? 0.f : vn;
          qp[tj] += s ? 1.f : 0.f;
        }
      }
    }
    int h = (m_blk >> 6) + wm;
#pragma unroll
    for (int tj = 0; tj < 4; ++tj) {
      float q = qp[tj];
      q += __shfl_xor(q, 16, 64);
      q += __shfl_xor(q, 32, 64);  // sum over quad -> full 64-channel head sum
      float vn = va[tj] + 0.5f * (q - va[tj]);  // exact dyadic
      bool s = vn >= 0.5f;
      va[tj] = s ? 0.f : vn;
      if (quad == 0) {
        int col = n_blk + wn * 64 + tj * 16 + l16;
        dout[(size_t)YSZ + ((size_t)(t * 16 + b) * 8 + h) * 1024 + col] = s ? 1.f : 0.f;
      }
    }
  }
}

// =====================================================================
// gemm_k: fused conv_k + BN + LIF + (spike * attn) -> y2b bitpacked
// [t,b,n, 64B of c-bits]. Same r0-geometry main loop as gemm_q.
// Output bitpack via shuffle-assemble (quad lanes hold 4 bits each ->
// 2x shfl_xor -> u16 per 16 channels), tiny 2.5 KB LDS transpose,
// coalesced 8 B stores. No big Ys tile, no bank-conflict surface.
// =====================================================================
__global__ __launch_bounds__(256, 2) void gemm_k_kernel(
    const u16* __restrict__ A, const u8* __restrict__ xsb,
    const float* __restrict__ consts, const float* __restrict__ dout,
    u8* __restrict__ y2b) {
  const int tid = threadIdx.x;
  const int lane = tid & 63, w = tid >> 6;
  const int wm = w >> 1, wn = w & 1;
  const int quad = lane >> 4, l16 = lane & 15;
  const int b = blockIdx.z;
  const int m_blk = blockIdx.y * 128, n_blk = blockIdx.x * 128;
  const int srow = lane >> 3;
  const int scol = (((lane & 7) ^ srow) & 7) * 8;
  __shared__ __align__(16) u16 smem[2 * 8192];  // Ash | Asl (32 KB); Ysb aliased
  u16* Ash = smem;
  u16* Asl = smem + 8192;
  u16* Ysb = smem;  // 128 rows x 10 u16 (2.5 KB), aliases Ash (dead after K-loop)
  const int rxor = l16 & 7;
  const int brow = n_blk + wn * 64 + l16;
  float v[64];
#pragma unroll
  for (int i = 0; i < 64; ++i) v[i] = 0.f;

  for (int t = 0; t < 4; ++t) {
    f32x4 acc[4][4];
    const f32x4 zero = {0.f, 0.f, 0.f, 0.f};
#pragma unroll
    for (int i = 0; i < 4; ++i)
#pragma unroll
      for (int j = 0; j < 4; ++j) acc[i][j] = zero;
    const u8* bitsT = xsb + (size_t)(t * 16 + b) * (N_ * 64);

    for (int k0 = 0; k0 < 512; k0 += 64) {
#pragma unroll
      for (int i = 0; i < 4; ++i) {
        int r = i * 32 + w * 8 + srow;
        int lo = (i * 32 + w * 8) * 64;
        async16(A + (size_t)(m_blk + r) * 1024 + k0 + scol, &Ash[lo]);
        async16(A + (size_t)(m_blk + r) * 1024 + 512 + k0 + scol, &Asl[lo]);
      }
      uint2 g[4];
#pragma unroll
      for (int tj = 0; tj < 4; ++tj)
        g[tj] = *(const uint2*)&bitsT[(size_t)(brow + tj * 16) * 64 + (k0 >> 3)];
      __syncthreads();
#pragma unroll
      for (int kk = 0; kk < 2; ++kk) {
        s16x8 ah[4], al[4], bf[4];
        const int slot = ((kk * 4 + quad) ^ rxor) * 8;
#pragma unroll
        for (int ti = 0; ti < 4; ++ti) {
          ah[ti] = *(const s16x8*)&Ash[(wm * 64 + ti * 16 + l16) * 64 + slot];
          al[ti] = *(const s16x8*)&Asl[(wm * 64 + ti * 16 + l16) * 64 + slot];
        }
#pragma unroll
        for (int tj = 0; tj < 4; ++tj) {
          u32 wb = kk ? g[tj].y : g[tj].x;
          bf[tj] = expand8((wb >> (quad * 8)) & 0xFFu);
        }
#pragma unroll
        for (int ti = 0; ti < 4; ++ti)
#pragma unroll
          for (int tj = 0; tj < 4; ++tj) {
            acc[ti][tj] = __builtin_amdgcn_mfma_f32_16x16x32_bf16(ah[ti], bf[tj], acc[ti][tj], 0, 0, 0);
            acc[ti][tj] = __builtin_amdgcn_mfma_f32_16x16x32_bf16(al[ti], bf[tj], acc[ti][tj], 0, 0, 0);
          }
      }
      __syncthreads();
    }

    // attn for this block's head/cols (head = (m_blk>>6)+wm, written by gemm_q)
    int h = (m_blk >> 6) + wm;
    float at[4];
#pragma unroll
    for (int tj = 0; tj < 4; ++tj) {
      int col = n_blk + wn * 64 + tj * 16 + l16;
      at[tj] = dout[(size_t)YSZ + ((size_t)(t * 16 + b) * 8 + h) * 1024 + col];
    }

    // epilogue: BN + LIF + mask -> 4-bit nibbles; shuffle-assemble u16 per
    // (row n, 16-channel group); quad0 lanes write Ysb[n][wm*4+ti].
#pragma unroll
    for (int ti = 0; ti < 4; ++ti) {
      u32 nib[4] = {0u, 0u, 0u, 0u};
#pragma unroll
      for (int r = 0; r < 4; ++r) {
        int row = m_blk + wm * 64 + ti * 16 + quad * 4 + r;
        float iv = consts[1024 + row], ib = consts[1536 + row];
#pragma unroll
        for (int tj = 0; tj < 4; ++tj) {
          float bnv = acc[ti][tj][r] * iv + ib;
          float vv = v[(ti * 4 + tj) * 4 + r];
          float vn = vv + 0.5f * (bnv - vv);
          bool s = vn >= 1.0f;
          v[(ti * 4 + tj) * 4 + r] = s ? 0.f : vn;
          nib[tj] |= (s && at[tj] != 0.f) ? (1u << r) : 0u;
        }
      }
#pragma unroll
      for (int tj = 0; tj < 4; ++tj) {
        u32 v16 = nib[tj] | (((u32)__shfl_xor((int)nib[tj], 16, 64)) << 4);
        v16 = v16 | (((u32)__shfl_xor((int)v16, 32, 64)) << 8);
        if (quad == 0) {
          int n_loc = wn * 64 + tj * 16 + l16;
          Ysb[n_loc * 10 + wm * 4 + ti] = (u16)v16;
        }
      }
    }
    __syncthreads();
    // coalesced store: 256 threads x 8 B = 128 rows x 16 B of c-bits
    {
      u8* yb = y2b + ((size_t)(t * 16 + b) * 1024 + n_blk) * 64 + (m_blk >> 3);
      int rown = tid >> 1, half = tid & 1;
      const u16* src = &Ysb[rown * 10 + half * 4];
      uint2 pv;
      pv.x = (u32)src[0] | ((u32)src[1] << 16);
      pv.y = (u32)src[2] | ((u32)src[3] << 16);
      *(uint2*)&yb[(size_t)rown * 64 + half * 8] = pv;
    }
    __syncthreads();  // Ysb dead before next t's staging overwrites smem
  }
}

// =====================================================================
// gemm_proj: out[d,n] = (sum_k pw[d,k]*y[n,k] + proj_b)*p_inv + p_bias.
// B operand (y spikes) from y2b bits, reg-direct + expand.
// =====================================================================
__global__ __launch_bounds__(256, 3) void gemm_proj_kernel(
    const u16* __restrict__ A, const u8* __restrict__ y2b,
    float* __restrict__ outP, const float* __restrict__ projb,
    const float* __restrict__ consts) {
  const int tid = threadIdx.x;
  const int lane = tid & 63, w = tid >> 6;
  const int wm = w >> 1, wn = w & 1;
  const int quad = lane >> 4, l16 = lane & 15;
  const int tb = blockIdx.z;
  const int m_blk = blockIdx.y * 128, n_blk = blockIdx.x * 128;
  const int srow = lane >> 3;
  const int scol = (((lane & 7) ^ srow) & 7) * 8;
  __shared__ __align__(16) u16 As[128 * 64];
  f32x4 acc[4][4];
  const f32x4 zero = {0.f, 0.f, 0.f, 0.f};
#pragma unroll
  for (int i = 0; i < 4; ++i)
#pragma unroll
    for (int j = 0; j < 4; ++j) acc[i][j] = zero;
  const u8* bitsT = y2b + (size_t)tb * (N_ * 64);
  const int rxor = l16 & 7;
  const int browb = n_blk + wn * 64 + l16;

  for (int k0 = 0; k0 < 512; k0 += 64) {
#pragma unroll
    for (int i = 0; i < 4; ++i) {
      int r = i * 32 + w * 8 + srow;
      async16(A + (size_t)(m_blk + r) * 512 + k0 + scol, &As[(i * 32 + w * 8) * 64]);
    }
    uint2 g[4];
#pragma unroll
    for (int tj = 0; tj < 4; ++tj)
      g[tj] = *(const uint2*)&bitsT[(size_t)(browb + tj * 16) * 64 + (k0 >> 3)];
    __syncthreads();
#pragma unroll
    for (int kk = 0; kk < 2; ++kk) {
      s16x8 af[4], bf[4];
      const int slot = ((kk * 4 + quad) ^ rxor) * 8;
#pragma unroll
      for (int ti = 0; ti < 4; ++ti)
        af[ti] = *(const s16x8*)&As[(wm * 64 + ti * 16 + l16) * 64 + slot];
#pragma unroll
      for (int tj = 0; tj < 4; ++tj) {
        u32 wbits = kk ? g[tj].y : g[tj].x;
        bf[tj] = expand8((wbits >> (quad * 8)) & 0xFFu);
      }
#pragma unroll
      for (int ti = 0; ti < 4; ++ti)
#pragma unroll
        for (int tj = 0; tj < 4; ++tj)
          acc[ti][tj] = __builtin_amdgcn_mfma_f32_16x16x32_bf16(af[ti], bf[tj], acc[ti][tj], 0, 0, 0);
    }
    __syncthreads();
  }

  const float* pinv = consts + 2048;
  const float* pb2 = consts + 2560;
  float* o = outP + (size_t)tb * (C_ * N_);
#pragma unroll
  for (int ti = 0; ti < 4; ++ti) {
    int row0 = m_blk + wm * 64 + ti * 16 + quad * 4;
#pragma unroll
    for (int r = 0; r < 4; ++r) {
      int row = row0 + r;
      float bi = projb[row], piv = pinv[row], pbi = pb2[row];
#pragma unroll
      for (int tj = 0; tj < 4; ++tj) {
        int col = n_blk + wn * 64 + tj * 16 + l16;
        o[(size_t)row * N_ + col] = (acc[ti][tj][r] + bi) * piv + pbi;
      }
    }
  }
}

// =====================================================================
extern "C" void kernel_launch(void* const* d_in, const int* in_sizes, int n_in,
                              void* d_out, int out_size, void* d_ws, size_t ws_size,
                              hipStream_t stream) {
  const float* x   = (const float*)d_in[0];
  const float* qw  = (const float*)d_in[1];
  const float* qg  = (const float*)d_in[2];
  const float* qb  = (const float*)d_in[3];
  const float* qm  = (const float*)d_in[4];
  const float* qv  = (const float*)d_in[5];
  const float* kw  = (const float*)d_in[6];
  const float* kg  = (const float*)d_in[7];
  const float* kb  = (const float*)d_in[8];
  const float* km  = (const float*)d_in[9];
  const float* kv  = (const float*)d_in[10];
  const float* pw  = (const float*)d_in[11];
  const float* pb  = (const float*)d_in[12];
  const float* pg  = (const float*)d_in[13];
  const float* pbt = (const float*)d_in[14];
  const float* pm  = (const float*)d_in[15];
  const float* pv  = (const float*)d_in[16];
  float* out = (float*)d_out;
  char* ws = (char*)d_ws;

  u8*  xsb      = (u8*)ws;                     // 4 MB spike bits [t,b,n, 64B]
  u8*  y2b      = (u8*)(ws + 4194304);         // 4 MB y spike bits [t,b,n, 64B]
  u16* whlq     = (u16*)(ws + 8388608);        // 1 MB
  u16* whlk     = (u16*)(ws + 9437184);        // 1 MB
  u16* pwb      = (u16*)(ws + 10485760);       // 512 KB
  float* consts = (float*)(ws + 11010048);     // 12 KB

  prep_kernel<<<513, 256, 0, stream>>>(qw, kw, pw, qg, qb, qm, qv, kg, kb, km, kv,
                                       pg, pbt, pm, pv, whlq, whlk, pwb, consts);
  lifx_kernel<<<dim3(16, 8, 16), 256, 0, stream>>>(x, xsb);
  gemm_q_kernel<<<dim3(8, 4, 16), 256, 0, stream>>>(whlq, xsb, consts, out);
  gemm_k_kernel<<<dim3(8, 4, 16), 256, 0, stream>>>(whlk, xsb, consts, out, y2b);
  gemm_proj_kernel<<<dim3(8, 4, 64), 256, 0, stream>>>(pwb, y2b, out, pb, consts);
}

// Round 5
// 401.230 us; speedup vs baseline: 1.2666x; 1.1204x over previous
//
#include <hip/hip_runtime.h>

typedef unsigned char u8;
typedef unsigned short u16;
typedef unsigned int u32;
typedef float f32x4 __attribute__((ext_vector_type(4)));
typedef short s16x8 __attribute__((ext_vector_type(8)));

#define T_ 4
#define B_ 16
#define C_ 512
#define N_ 1024
#define YSZ 33554432  // 64*512*1024 (y output elements); attn follows in d_out

// ---- bf16 helpers (manual RNE) ----
__device__ __forceinline__ u16 f2bf(float f) {
  u32 u = __float_as_uint(f);
  u32 r = u + 0x7FFFu + ((u >> 16) & 1u);
  return (u16)(r >> 16);
}
__device__ __forceinline__ float bf2f(u16 h) { return __uint_as_float(((u32)h) << 16); }

// ---- async global->LDS, 16B per lane, wave-uniform LDS base ----
__device__ __forceinline__ void async16(const void* g, void* l) {
  __builtin_amdgcn_global_load_lds((const __attribute__((address_space(1))) void*)g,
                                   (__attribute__((address_space(3))) void*)l, 16, 0, 0);
}

// ---- expand 8 spike bits -> 8 bf16 {0,1.0} (s16x8 MFMA operand) ----
__device__ __forceinline__ s16x8 expand8(u32 m) {
  union { u32 w[4]; s16x8 v; } u;
  u.w[0] = (m & 1u   ? 0x3F80u : 0u) | (m & 2u   ? 0x3F800000u : 0u);
  u.w[1] = (m & 4u   ? 0x3F80u : 0u) | (m & 8u   ? 0x3F800000u : 0u);
  u.w[2] = (m & 16u  ? 0x3F80u : 0u) | (m & 32u  ? 0x3F800000u : 0u);
  u.w[3] = (m & 64u  ? 0x3F80u : 0u) | (m & 128u ? 0x3F800000u : 0u);
  return u.v;
}

// =====================================================================
// prep: split q_w/k_w into bf16 hi|lo concat [512][1024]; proj_w -> bf16;
//       BN constants (inv, bias) for q/k/p into consts[].
// =====================================================================
__global__ void prep_kernel(const float* __restrict__ qw, const float* __restrict__ kw,
                            const float* __restrict__ pw,
                            const float* __restrict__ qg, const float* __restrict__ qb,
                            const float* __restrict__ qm, const float* __restrict__ qv,
                            const float* __restrict__ kg, const float* __restrict__ kb,
                            const float* __restrict__ km, const float* __restrict__ kv,
                            const float* __restrict__ pg, const float* __restrict__ pbt,
                            const float* __restrict__ pm, const float* __restrict__ pv,
                            u16* __restrict__ whlq, u16* __restrict__ whlk,
                            u16* __restrict__ pwb, float* __restrict__ consts) {
  int blk = blockIdx.x, tid = threadIdx.x;
  if (blk < 512) {
    int d = blk;
    for (int c = tid; c < 512; c += 256) {
      float w = qw[d * 512 + c];
      u16 hi = f2bf(w);
      whlq[d * 1024 + c] = hi;
      whlq[d * 1024 + 512 + c] = f2bf(w - bf2f(hi));
      w = kw[d * 512 + c];
      hi = f2bf(w);
      whlk[d * 1024 + c] = hi;
      whlk[d * 1024 + 512 + c] = f2bf(w - bf2f(hi));
      pwb[d * 512 + c] = f2bf(pw[d * 512 + c]);
    }
  } else {
    for (int c = tid; c < 512; c += 256) {
      float inv = qg[c] / sqrtf(qv[c] + 1e-5f);
      consts[c] = inv; consts[512 + c] = qb[c] - qm[c] * inv;
      inv = kg[c] / sqrtf(kv[c] + 1e-5f);
      consts[1024 + c] = inv; consts[1536 + c] = kb[c] - km[c] * inv;
      inv = pg[c] / sqrtf(pv[c] + 1e-5f);
      consts[2048 + c] = inv; consts[2560 + c] = pbt[c] - pm[c] * inv;
    }
  }
}

// =====================================================================
// lif_x: x[t,b,c,n] f32 -> bitpacked spikes xsb[t,b,n, 64B of c-bits].
// bit j of byte cb  <->  c = cb*8 + j.
// =====================================================================
__global__ __launch_bounds__(256) void lifx_kernel(const float* __restrict__ x,
                                                   u8* __restrict__ xsb) {
  int b = blockIdx.z;
  int cbase = blockIdx.y * 64, nbase = blockIdx.x * 64;
  int tid = threadIdx.x;
  int c_l = tid >> 6, n_l = tid & 63;
  float v[16];
#pragma unroll
  for (int i = 0; i < 16; ++i) v[i] = 0.f;
  for (int t = 0; t < 4; ++t) {
    const float* xp = x + ((size_t)(t * 16 + b) * 512 + cbase + c_l * 16) * 1024 + nbase + n_l;
    u32 mask = 0;
#pragma unroll
    for (int i = 0; i < 16; ++i) {
      float xv = xp[(size_t)i * 1024];
      float vn = v[i] + 0.5f * (xv - v[i]);   // v + (x-v)/TAU, TAU=2 (bit-exact vs np)
      bool s = vn >= 1.0f;
      mask |= (s ? 1u : 0u) << i;
      v[i] = s ? 0.f : vn;
    }
    *(u16*)&xsb[((size_t)(t * 16 + b) * 1024 + nbase + n_l) * 64 + (cbase >> 3) + c_l * 2] =
        (u16)mask;
  }
}

// =====================================================================
// All-t batched K-loop shared by gemm_q / gemm_k.
// Block: BM=128 x BN=128, 8 waves (2m x 4n), per-wave 64x32 x 4 timesteps.
// acc[t][ti][tj]: all 4 timesteps accumulated in one K pass (LIF state is
// epilogue-only, so this is a pure loop interchange -- A hi/lo staged ONCE
// per k0 instead of 4x, MFMA per staged byte 4x r0's).
// A: double-buffered LDS (2 x 32 KB), staged issue-early, ONE barrier/k0.
// B: bitpacked spikes global->reg (uint2 per t,tj; one 64B line per row
// covers the whole K range), expanded in-register to {0,1.0}bf16.
// Per-accumulator MFMA order: k0 asc, kk asc, hi, lo -- identical to r0.
// =====================================================================
__device__ __forceinline__ void qk_mainloop_allt(
    const u16* __restrict__ A, const u8* __restrict__ xsb, u16* sm,
    int b, int m_blk, int n_blk, int wid, int wm, int wn,
    int quad, int l16, int srow, int scol, int rxor,
    f32x4 (&acc)[4][4][2]) {
  const int arow = wid * 8 + srow;
  const u8* bbase = xsb + ((size_t)b * N_ + n_blk + wn * 32 + l16) * 64;

  // prologue: stage k0=0 into buf0; load bits k0=0
#pragma unroll
  for (int i = 0; i < 2; ++i) {
    int r = i * 64 + arow;
    int lo = (i * 64 + wid * 8) * 64;
    async16(A + (size_t)(m_blk + r) * 1024 + scol, &sm[lo]);
    async16(A + (size_t)(m_blk + r) * 1024 + 512 + scol, &sm[8192 + lo]);
  }
  uint2 g[4][2], gN[4][2];
#pragma unroll
  for (int t = 0; t < 4; ++t)
#pragma unroll
    for (int tj = 0; tj < 2; ++tj)
      g[t][tj] = *(const uint2*)(bbase + (size_t)t * 1048576 + tj * 1024);
  __syncthreads();

  int cur = 0;
  for (int s = 0; s < 8; ++s) {
    if (s < 7) {  // issue next-k0 stage + bits early; they land under compute
      const int k0n = (s + 1) * 64;
      u16* D = sm + (cur ^ 1) * 16384;
#pragma unroll
      for (int i = 0; i < 2; ++i) {
        int r = i * 64 + arow;
        int lo = (i * 64 + wid * 8) * 64;
        async16(A + (size_t)(m_blk + r) * 1024 + k0n + scol, &D[lo]);
        async16(A + (size_t)(m_blk + r) * 1024 + 512 + k0n + scol, &D[8192 + lo]);
      }
#pragma unroll
      for (int t = 0; t < 4; ++t)
#pragma unroll
        for (int tj = 0; tj < 2; ++tj)
          gN[t][tj] = *(const uint2*)(bbase + (size_t)t * 1048576 + tj * 1024 + (k0n >> 3));
    }
    const u16* Ash = sm + cur * 16384;
    const u16* Asl = Ash + 8192;
#pragma unroll
    for (int kk = 0; kk < 2; ++kk) {
      s16x8 ah[4], al[4];
      const int slot = ((kk * 4 + quad) ^ rxor) * 8;
#pragma unroll
      for (int ti = 0; ti < 4; ++ti) {
        ah[ti] = *(const s16x8*)&Ash[(wm * 64 + ti * 16 + l16) * 64 + slot];
        al[ti] = *(const s16x8*)&Asl[(wm * 64 + ti * 16 + l16) * 64 + slot];
      }
#pragma unroll
      for (int t = 0; t < 4; ++t) {
        s16x8 bf0 = expand8(((kk ? g[t][0].y : g[t][0].x) >> (quad * 8)) & 0xFFu);
        s16x8 bf1 = expand8(((kk ? g[t][1].y : g[t][1].x) >> (quad * 8)) & 0xFFu);
#pragma unroll
        for (int ti = 0; ti < 4; ++ti) {
          acc[t][ti][0] = __builtin_amdgcn_mfma_f32_16x16x32_bf16(ah[ti], bf0, acc[t][ti][0], 0, 0, 0);
          acc[t][ti][0] = __builtin_amdgcn_mfma_f32_16x16x32_bf16(al[ti], bf0, acc[t][ti][0], 0, 0, 0);
          acc[t][ti][1] = __builtin_amdgcn_mfma_f32_16x16x32_bf16(ah[ti], bf1, acc[t][ti][1], 0, 0, 0);
          acc[t][ti][1] = __builtin_amdgcn_mfma_f32_16x16x32_bf16(al[ti], bf1, acc[t][ti][1], 0, 0, 0);
        }
      }
    }
    __syncthreads();  // drains next-buf stage (covered by compute); reads of cur done
    if (s < 7) {
#pragma unroll
      for (int t = 0; t < 4; ++t)
#pragma unroll
        for (int tj = 0; tj < 2; ++tj) g[t][tj] = gN[t][tj];
    }
    cur ^= 1;
  }
}

// =====================================================================
// gemm_q: fused conv_q + BN + LIF + head-sum + attn-LIF (all t in one pass).
// =====================================================================
__global__ __launch_bounds__(512, 2) void gemm_q_kernel(
    const u16* __restrict__ A, const u8* __restrict__ xsb,
    const float* __restrict__ consts, float* __restrict__ dout) {
  extern __shared__ u16 sm[];  // 2 x (Ash 8192 | Asl 8192) u16 = 64 KB
  const int tid = threadIdx.x;
  const int lane = tid & 63, wid = tid >> 6;
  const int wm = wid >> 2, wn = wid & 3;
  const int quad = lane >> 4, l16 = lane & 15;
  const int b = blockIdx.z;
  const int m_blk = blockIdx.y * 128, n_blk = blockIdx.x * 128;
  const int srow = lane >> 3;
  const int scol = (((lane & 7) ^ srow) & 7) * 8;
  const int rxor = l16 & 7;

  f32x4 acc[4][4][2];
  const f32x4 zero = {0.f, 0.f, 0.f, 0.f};
#pragma unroll
  for (int t = 0; t < 4; ++t)
#pragma unroll
    for (int i = 0; i < 4; ++i)
#pragma unroll
      for (int j = 0; j < 2; ++j) acc[t][i][j] = zero;

  qk_mainloop_allt(A, xsb, sm, b, m_blk, n_blk, wid, wm, wn, quad, l16, srow, scol, rxor, acc);

  // epilogue: t ascending -- BN + LIF + head-sum + attn-LIF (wave = one head)
  float v[32];
#pragma unroll
  for (int i = 0; i < 32; ++i) v[i] = 0.f;
  float va[2] = {0.f, 0.f};
  const int h = (m_blk >> 6) + wm;
#pragma unroll
  for (int t = 0; t < 4; ++t) {
    float qp[2] = {0.f, 0.f};
#pragma unroll
    for (int ti = 0; ti < 4; ++ti) {
#pragma unroll
      for (int r = 0; r < 4; ++r) {
        int row = m_blk + wm * 64 + ti * 16 + quad * 4 + r;
        float iv = consts[row], ib = consts[512 + row];
#pragma unroll
        for (int tj = 0; tj < 2; ++tj) {
          float bnv = acc[t][ti][tj][r] * iv + ib;
          float vv = v[(ti * 2 + tj) * 4 + r];
          float vn = vv + 0.5f * (bnv - vv);
          bool s = vn >= 1.0f;
          v[(ti * 2 + tj) * 4 + r] = s ? 0.f : vn;
          qp[tj] += s ? 1.f : 0.f;
        }
      }
    }
#pragma unroll
    for (int tj = 0; tj < 2; ++tj) {
      float q = qp[tj];
      q += __shfl_xor(q, 16, 64);
      q += __shfl_xor(q, 32, 64);  // full 64-channel head sum
      float vn = va[tj] + 0.5f * (q - va[tj]);  // exact dyadic
      bool s = vn >= 0.5f;
      va[tj] = s ? 0.f : vn;
      if (quad == 0) {
        int col = n_blk + wn * 32 + tj * 16 + l16;
        dout[(size_t)YSZ + ((size_t)(t * 16 + b) * 8 + h) * 1024 + col] = s ? 1.f : 0.f;
      }
    }
  }
}

// =====================================================================
// gemm_k: fused conv_k + BN + LIF + (spike * attn) -> y2b bitpacked
// [t,b,n, 64B of c-bits]. Same all-t main loop; per-t epilogue bitpacks
// via quad shfl-assemble into a tiny 2.5 KB LDS tile (aliases staging).
// =====================================================================
__global__ __launch_bounds__(512, 2) void gemm_k_kernel(
    const u16* __restrict__ A, const u8* __restrict__ xsb,
    const float* __restrict__ consts, const float* __restrict__ dout,
    u8* __restrict__ y2b) {
  extern __shared__ u16 sm[];
  const int tid = threadIdx.x;
  const int lane = tid & 63, wid = tid >> 6;
  const int wm = wid >> 2, wn = wid & 3;
  const int quad = lane >> 4, l16 = lane & 15;
  const int b = blockIdx.z;
  const int m_blk = blockIdx.y * 128, n_blk = blockIdx.x * 128;
  const int srow = lane >> 3;
  const int scol = (((lane & 7) ^ srow) & 7) * 8;
  const int rxor = l16 & 7;

  f32x4 acc[4][4][2];
  const f32x4 zero = {0.f, 0.f, 0.f, 0.f};
#pragma unroll
  for (int t = 0; t < 4; ++t)
#pragma unroll
    for (int i = 0; i < 4; ++i)
#pragma unroll
      for (int j = 0; j < 2; ++j) acc[t][i][j] = zero;

  qk_mainloop_allt(A, xsb, sm, b, m_blk, n_blk, wid, wm, wn, quad, l16, srow, scol, rxor, acc);

  u16* Ysb = sm;  // 128 rows x 10 u16 (2.5 KB), staging dead after K-loop
  float v[32];
#pragma unroll
  for (int i = 0; i < 32; ++i) v[i] = 0.f;
  const int h = (m_blk >> 6) + wm;
#pragma unroll
  for (int t = 0; t < 4; ++t) {
    float at[2];
#pragma unroll
    for (int tj = 0; tj < 2; ++tj) {
      int col = n_blk + wn * 32 + tj * 16 + l16;
      at[tj] = dout[(size_t)YSZ + ((size_t)(t * 16 + b) * 8 + h) * 1024 + col];
    }
#pragma unroll
    for (int ti = 0; ti < 4; ++ti) {
      u32 nib[2] = {0u, 0u};
#pragma unroll
      for (int r = 0; r < 4; ++r) {
        int row = m_blk + wm * 64 + ti * 16 + quad * 4 + r;
        float iv = consts[1024 + row], ib = consts[1536 + row];
#pragma unroll
        for (int tj = 0; tj < 2; ++tj) {
          float bnv = acc[t][ti][tj][r] * iv + ib;
          float vv = v[(ti * 2 + tj) * 4 + r];
          float vn = vv + 0.5f * (bnv - vv);
          bool s = vn >= 1.0f;
          v[(ti * 2 + tj) * 4 + r] = s ? 0.f : vn;
          nib[tj] |= (s && at[tj] != 0.f) ? (1u << r) : 0u;
        }
      }
#pragma unroll
      for (int tj = 0; tj < 2; ++tj) {
        u32 v16 = nib[tj] | (((u32)__shfl_xor((int)nib[tj], 16, 64)) << 4);
        v16 = v16 | (((u32)__shfl_xor((int)v16, 32, 64)) << 8);
        if (quad == 0) {
          int n_loc = wn * 32 + tj * 16 + l16;
          Ysb[n_loc * 10 + wm * 4 + ti] = (u16)v16;
        }
      }
    }
    __syncthreads();
    // coalesced store: 128 rows x 16 B of c-bits; 512 thr x 4 B
    {
      u8* yb = y2b + ((size_t)(t * 16 + b) * 1024 + n_blk) * 64 + (m_blk >> 3);
      int rown = tid >> 2, part = tid & 3;
      const u16* src = &Ysb[rown * 10 + part * 2];
      u32 pv = (u32)src[0] | ((u32)src[1] << 16);
      *(u32*)&yb[(size_t)rown * 64 + part * 4] = pv;
    }
    __syncthreads();  // Ysb reusable for next t
  }
}

// =====================================================================
// gemm_proj: out[d,n] = (sum_k pw[d,k]*y[n,k] + proj_b)*p_inv + p_bias.
// B operand (y spikes) from y2b bits, reg-direct + expand. (r4 form.)
// =====================================================================
__global__ __launch_bounds__(256, 3) void gemm_proj_kernel(
    const u16* __restrict__ A, const u8* __restrict__ y2b,
    float* __restrict__ outP, const float* __restrict__ projb,
    const float* __restrict__ consts) {
  const int tid = threadIdx.x;
  const int lane = tid & 63, w = tid >> 6;
  const int wm = w >> 1, wn = w & 1;
  const int quad = lane >> 4, l16 = lane & 15;
  const int tb = blockIdx.z;
  const int m_blk = blockIdx.y * 128, n_blk = blockIdx.x * 128;
  const int srow = lane >> 3;
  const int scol = (((lane & 7) ^ srow) & 7) * 8;
  __shared__ __align__(16) u16 As[128 * 64];
  f32x4 acc[4][4];
  const f32x4 zero = {0.f, 0.f, 0.f, 0.f};
#pragma unroll
  for (int i = 0; i < 4; ++i)
#pragma unroll
    for (int j = 0; j < 4; ++j) acc[i][j] = zero;
  const u8* bitsT = y2b + (size_t)tb * (N_ * 64);
  const int rxor = l16 & 7;
  const int browb = n_blk + wn * 64 + l16;

  for (int k0 = 0; k0 < 512; k0 += 64) {
#pragma unroll
    for (int i = 0; i < 4; ++i) {
      int r = i * 32 + w * 8 + srow;
      async16(A + (size_t)(m_blk + r) * 512 + k0 + scol, &As[(i * 32 + w * 8) * 64]);
    }
    uint2 g[4];
#pragma unroll
    for (int tj = 0; tj < 4; ++tj)
      g[tj] = *(const uint2*)&bitsT[(size_t)(browb + tj * 16) * 64 + (k0 >> 3)];
    __syncthreads();
#pragma unroll
    for (int kk = 0; kk < 2; ++kk) {
      s16x8 af[4], bf[4];
      const int slot = ((kk * 4 + quad) ^ rxor) * 8;
#pragma unroll
      for (int ti = 0; ti < 4; ++ti)
        af[ti] = *(const s16x8*)&As[(wm * 64 + ti * 16 + l16) * 64 + slot];
#pragma unroll
      for (int tj = 0; tj < 4; ++tj) {
        u32 wbits = kk ? g[tj].y : g[tj].x;
        bf[tj] = expand8((wbits >> (quad * 8)) & 0xFFu);
      }
#pragma unroll
      for (int ti = 0; ti < 4; ++ti)
#pragma unroll
        for (int tj = 0; tj < 4; ++tj)
          acc[ti][tj] = __builtin_amdgcn_mfma_f32_16x16x32_bf16(af[ti], bf[tj], acc[ti][tj], 0, 0, 0);
    }
    __syncthreads();
  }

  const float* pinv = consts + 2048;
  const float* pb2 = consts + 2560;
  float* o = outP + (size_t)tb * (C_ * N_);
#pragma unroll
  for (int ti = 0; ti < 4; ++ti) {
    int row0 = m_blk + wm * 64 + ti * 16 + quad * 4;
#pragma unroll
    for (int r = 0; r < 4; ++r) {
      int row = row0 + r;
      float bi = projb[row], piv = pinv[row], pbi = pb2[row];
#pragma unroll
      for (int tj = 0; tj < 4; ++tj) {
        int col = n_blk + wn * 64 + tj * 16 + l16;
        o[(size_t)row * N_ + col] = (acc[ti][tj][r] + bi) * piv + pbi;
      }
    }
  }
}

// =====================================================================
extern "C" void kernel_launch(void* const* d_in, const int* in_sizes, int n_in,
                              void* d_out, int out_size, void* d_ws, size_t ws_size,
                              hipStream_t stream) {
  const float* x   = (const float*)d_in[0];
  const float* qw  = (const float*)d_in[1];
  const float* qg  = (const float*)d_in[2];
  const float* qb  = (const float*)d_in[3];
  const float* qm  = (const float*)d_in[4];
  const float* qv  = (const float*)d_in[5];
  const float* kw  = (const float*)d_in[6];
  const float* kg  = (const float*)d_in[7];
  const float* kb  = (const float*)d_in[8];
  const float* km  = (const float*)d_in[9];
  const float* kv  = (const float*)d_in[10];
  const float* pw  = (const float*)d_in[11];
  const float* pb  = (const float*)d_in[12];
  const float* pg  = (const float*)d_in[13];
  const float* pbt = (const float*)d_in[14];
  const float* pm  = (const float*)d_in[15];
  const float* pv  = (const float*)d_in[16];
  float* out = (float*)d_out;
  char* ws = (char*)d_ws;

  u8*  xsb      = (u8*)ws;                     // 4 MB spike bits [t,b,n, 64B]
  u8*  y2b      = (u8*)(ws + 4194304);         // 4 MB y spike bits [t,b,n, 64B]
  u16* whlq     = (u16*)(ws + 8388608);        // 1 MB
  u16* whlk     = (u16*)(ws + 9437184);        // 1 MB
  u16* pwb      = (u16*)(ws + 10485760);       // 512 KB
  float* consts = (float*)(ws + 11010048);     // 12 KB

  static int attr_done = 0;
  if (!attr_done) {
    hipFuncSetAttribute((const void*)gemm_q_kernel,
                        hipFuncAttributeMaxDynamicSharedMemorySize, 65536);
    hipFuncSetAttribute((const void*)gemm_k_kernel,
                        hipFuncAttributeMaxDynamicSharedMemorySize, 65536);
    attr_done = 1;
  }

  prep_kernel<<<513, 256, 0, stream>>>(qw, kw, pw, qg, qb, qm, qv, kg, kb, km, kv,
                                       pg, pbt, pm, pv, whlq, whlk, pwb, consts);
  lifx_kernel<<<dim3(16, 8, 16), 256, 0, stream>>>(x, xsb);
  gemm_q_kernel<<<dim3(8, 4, 16), 512, 65536, stream>>>(whlq, xsb, consts, out);
  gemm_k_kernel<<<dim3(8, 4, 16), 512, 65536, stream>>>(whlk, xsb, consts, out, y2b);
  gemm_proj_kernel<<<dim3(8, 4, 64), 256, 0, stream>>>(pwb, y2b, out, pb, consts);
}